// Round 5
// baseline (1201.067 us; speedup 1.0000x reference)
//
#include <hip/hip_runtime.h>
#include <cstdint>
#include <cstddef>

// Problem constants
#define NB 256
#define SQ 500
#define NROWS (NB * SQ)   // 128000
#define DQ 128
#define DV 256
#define MM 50
#define FF 512
#define WSTRIDE 52        // padded w-row stride in the float layout (alloc sizing)
#define WHS 64            // fp16 w row stride (u16 units) = 128 B
#define WT 10             // scan ea-prefetch tile: steps per stage

typedef _Float16 half8 __attribute__((ext_vector_type(8)));
typedef float floatx4 __attribute__((ext_vector_type(4)));
typedef unsigned int u32;
typedef u32 u32x4 __attribute__((ext_vector_type(4)));
typedef unsigned short u16;

__device__ __forceinline__ float4 ld4(const float* p) {
    return *reinterpret_cast<const float4*>(p);
}
__device__ __forceinline__ float sigf(float x) { return 1.f / (1.f + __expf(-x)); }
__device__ __forceinline__ float tanhfast(float x) { return 2.f / (1.f + __expf(-2.f * x)) - 1.f; }
__device__ __forceinline__ int gmap(int l, int s0, int CS) {
    int b = (unsigned)l / (unsigned)CS;
    return b * SQ + s0 + (l - b * CS);
}
__device__ __forceinline__ void st4h(u16* dst, float4 v) {
    _Float16 h0 = (_Float16)v.x, h1 = (_Float16)v.y, h2 = (_Float16)v.z, h3 = (_Float16)v.w;
    ushort4 u;
    u.x = *(u16*)&h0; u.y = *(u16*)&h1; u.z = *(u16*)&h2; u.w = *(u16*)&h3;
    *(ushort4*)dst = u;
}
__device__ __forceinline__ float h2f(u16 b) { _Float16 h; *(u16*)&h = b; return (float)h; }
__device__ __forceinline__ u16 f2h(float x) { _Float16 h = (_Float16)x; return *(u16*)&h; }

// ---------------------------------------------------------------------------
// fp32 -> fp16 conversion (vec4)
// ---------------------------------------------------------------------------
__global__ __launch_bounds__(256) void cvt16(
    const float* __restrict__ s, u16* __restrict__ d, int n4)
{
    int i = blockIdx.x * 256 + threadIdx.x;
    if (i < n4) st4h(d + 4 * (size_t)i, ld4(s + 4 * (size_t)i));
}

// ---------------------------------------------------------------------------
// Mk [50,128] fp32 -> Mkh [64,128] fp16, rows 50..63 zeroed
// ---------------------------------------------------------------------------
__global__ __launch_bounds__(256) void mkcvt(
    const float* __restrict__ Mk, u16* __restrict__ Mkh)
{
    int i = blockIdx.x * 256 + threadIdx.x;   // 2048 float4 slots
    if (i >= 64 * 32) return;
    int row = i >> 5;
    float4 v = (row < MM) ? ld4(Mk + (size_t)row * DQ + (i & 31) * 4)
                          : float4{0.f, 0.f, 0.f, 0.f};
    st4h(Mkh + 4 * (size_t)i, v);
}

// ---------------------------------------------------------------------------
// prep: Xp rows [0,Nc) = fp16(te+qe); rows [Nc,2Nc) = fp16(he+hte+ae+qe);
//       S3p = fp16(he+hte+ae); QEp = fp16(qe)
// ---------------------------------------------------------------------------
__global__ __launch_bounds__(256) void prep128(
    const int* __restrict__ q_data, const int* __restrict__ time_data,
    const int* __restrict__ attempt_data, const int* __restrict__ hint_data,
    const int* __restrict__ hintT_data,
    const float* __restrict__ q_emb, const float* __restrict__ time_emb,
    const float* __restrict__ attempt_emb, const float* __restrict__ ht_emb,
    u16* __restrict__ Xp, u16* __restrict__ S3p, u16* __restrict__ QEp,
    int s0, int CS, int Nc)
{
    int g = blockIdx.x * 256 + threadIdx.x;
    int l = g >> 5;
    int kq = (g & 31) << 2;
    if (l >= Nc) return;
    int n = gmap(l, s0, CS);
    float4 qe  = ld4(q_emb       + (size_t)q_data[n]       * DQ + kq);
    float4 te  = ld4(time_emb    + (size_t)time_data[n]    * DQ + kq);
    float4 ae  = ld4(attempt_emb + (size_t)attempt_data[n] * DQ + kq);
    float4 he  = ld4(ht_emb      + (size_t)hint_data[n]    * DQ + kq);
    float4 hte = ld4(ht_emb      + (size_t)hintT_data[n]   * DQ + kq);
    size_t off = (size_t)l * DQ + kq;
    float4 x1, s3, x2;
    x1.x = te.x + qe.x; x1.y = te.y + qe.y; x1.z = te.z + qe.z; x1.w = te.w + qe.w;
    s3.x = he.x + hte.x + ae.x; s3.y = he.y + hte.y + ae.y;
    s3.z = he.z + hte.z + ae.z; s3.w = he.w + hte.w + ae.w;
    x2.x = s3.x + qe.x; x2.y = s3.y + qe.y; x2.z = s3.z + qe.z; x2.w = s3.w + qe.w;
    st4h(Xp + off, x1);
    st4h(Xp + (size_t)Nc * DQ + off, x2);
    st4h(S3p + off, s3);
    st4h(QEp + off, qe);
}

// ---------------------------------------------------------------------------
// fp16 MFMA GEMM: Y = epi(act(A @ W^T + bias)), BM=BN=128, BK=32, 4 waves,
// wave tile 64x64 = 4x4 of v_mfma_f32_16x16x32_f16.
// MODE 1: tanh -> fp16 Yh (stride 128)               [lin1 on 2Nc rows]
// MODE 2: sig; row<Nc: tf->Yh; row>=Nc: x3=qe+v*s3 -> Yh  [lin2 batched]
// MODE 3: none; qp->Yh; fused ie=qp+tf*te -> AUX[,256:384] [lin1(X3)+ew_ie]
// MODE 4: gather A=qaE[idx]; by<2: sig->e, else tanh->a; packed u16 pairs->AUX
// MODE 5: tanh(rc); pred-partial reduce -> atomicAdd Yf    [readout+pred]
// ---------------------------------------------------------------------------
template <int MODE>
__global__ __launch_bounds__(256, 3) void gemm16(
    const u16* __restrict__ A, const u16* __restrict__ W0,
    const u16* __restrict__ W1, const float* __restrict__ b0,
    const float* __restrict__ b1, u16* __restrict__ Yh,
    float* __restrict__ Yf,
    const u16* __restrict__ QEp, const u16* __restrict__ S3p,
    const int* __restrict__ idx, const float* __restrict__ gtab,
    u16* __restrict__ AUX, const float* __restrict__ predW,
    int K, int Nc, int s0, int CS)
{
    __shared__ u16 smem[2 * 128 * 40];   // 20480 B: A-tile | B-tile (pitch 80B)
    u16* At = smem;
    u16* Bt = smem + 128 * 40;
    const int tid = threadIdx.x;
    const int row0 = blockIdx.x * 128;
    const int by = blockIdx.y;

    const u16* Wp;
    int col0;
    if constexpr (MODE == 4) { Wp = (by < 2) ? W0 : W1; col0 = (by & 1) * 128; }
    else { Wp = W0; col0 = by * 128; }
    const float* bias = (MODE == 4 && by >= 2) ? b1 : b0;

    floatx4 acc[4][4];
#pragma unroll
    for (int m = 0; m < 4; ++m)
#pragma unroll
        for (int n = 0; n < 4; ++n) acc[m][n] = (floatx4)0.f;

    const int lane = tid & 63, wv = tid >> 6;
    const int wr = (wv >> 1) * 64, wc = (wv & 1) * 64;
    const int q = lane >> 4, c0 = lane & 15;

    for (int kt = 0; kt < K; kt += 32) {
#pragma unroll
        for (int i = 0; i < 4; ++i) {
            int c = tid + i * 256;          // [0,1024)
            if (c < 512) {
                int r = c >> 2, seg = c & 3;
                const u16* src;
                if constexpr (MODE == 4) {
                    int g = idx[gmap(row0 + r, s0, CS)];
                    src = A + (size_t)g * K + kt + seg * 8;
                } else {
                    src = A + (size_t)(row0 + r) * K + kt + seg * 8;
                }
                *(uint4*)&At[r * 40 + seg * 8] = *(const uint4*)src;
            } else {
                int cb = c - 512;
                int r = cb >> 2, seg = cb & 3;
                const u16* src = Wp + (size_t)(col0 + r) * K + kt + seg * 8;
                *(uint4*)&Bt[r * 40 + seg * 8] = *(const uint4*)src;
            }
        }
        __syncthreads();
        half8 af[4], bf[4];
#pragma unroll
        for (int m = 0; m < 4; ++m) af[m] = *(half8*)&At[(wr + m * 16 + c0) * 40 + q * 8];
#pragma unroll
        for (int n = 0; n < 4; ++n) bf[n] = *(half8*)&Bt[(wc + n * 16 + c0) * 40 + q * 8];
#pragma unroll
        for (int m = 0; m < 4; ++m)
#pragma unroll
            for (int n = 0; n < 4; ++n)
                acc[m][n] = __builtin_amdgcn_mfma_f32_16x16x32_f16(af[m], bf[n], acc[m][n], 0, 0, 0);
        __syncthreads();
    }

    float bv[4];
#pragma unroll
    for (int n = 0; n < 4; ++n) bv[n] = bias[col0 + wc + n * 16 + c0];

    if constexpr (MODE == 5) {
        float pw[4];
#pragma unroll
        for (int n = 0; n < 4; ++n) pw[n] = predW[col0 + wc + n * 16 + c0];
        float* red = (float*)smem;          // [128][33] = 16896 B <= 20480
#pragma unroll
        for (int m = 0; m < 4; ++m)
#pragma unroll
            for (int r4 = 0; r4 < 4; ++r4) {
                int row = wr + m * 16 + q * 4 + r4;
                float pp = 0.f;
#pragma unroll
                for (int n = 0; n < 4; ++n)
                    pp = fmaf(tanhfast(acc[m][n][r4] + bv[n]), pw[n], pp);
                red[row * 33 + (wv & 1) * 16 + c0] = pp;
            }
        __syncthreads();
        if (tid < 128) {
            float s = 0.f;
#pragma unroll
            for (int j = 0; j < 32; ++j) s += red[tid * 33 + j];
            atomicAdd(&Yf[row0 + tid], s);
        }
    } else {
#pragma unroll
        for (int m = 0; m < 4; ++m)
#pragma unroll
            for (int r4 = 0; r4 < 4; ++r4) {
                int row = row0 + wr + m * 16 + q * 4 + r4;
#pragma unroll
                for (int n = 0; n < 4; ++n) {
                    int col = col0 + wc + n * 16 + c0;
                    float v = acc[m][n][r4] + bv[n];
                    if constexpr (MODE == 1) {
                        Yh[(size_t)row * 128 + col] = f2h(tanhfast(v));
                    } else if constexpr (MODE == 2) {
                        v = sigf(v);
                        if (row < Nc) {
                            Yh[(size_t)row * 128 + col] = f2h(v);
                        } else {
                            size_t o = (size_t)(row - Nc) * 128 + col;
                            float qe = h2f(QEp[o]), s3 = h2f(S3p[o]);
                            Yh[(size_t)row * 128 + col] = f2h(fmaf(v, s3, qe));
                        }
                    } else if constexpr (MODE == 3) {
                        size_t o = (size_t)row * 128 + col;
                        float tf = h2f(Yh[o]);   // read tf BEFORE overwriting with qp
                        float te = gtab[(size_t)idx[gmap(row, s0, CS)] * 128 + col];
                        AUX[(size_t)row * 384 + 256 + col] = f2h(fmaf(tf, te, v));
                        Yh[o] = f2h(v);
                    } else { // MODE 4
                        bool isE = (by < 2);
                        v = isE ? sigf(v) : tanhfast(v);
                        AUX[((size_t)row * 256 + col) * 2 + (isE ? 0 : 1)] = f2h(v);
                    }
                }
            }
    }
}

// ---------------------------------------------------------------------------
// w = softmax(qp @ Mk^T) via MFMA. Block: 128 rows x 64 cols (50 live).
// Logits -> LDS (pitch 67), row softmax, then packed fp16 store to Wh
// (stride WHS=64 u16 = 128 B per row; cols 50..63 zeroed).
// ---------------------------------------------------------------------------
__global__ __launch_bounds__(256) void wsoftmax_mfma(
    const u16* __restrict__ QP, const u16* __restrict__ Mkh,
    u32* __restrict__ Wh)
{
    __shared__ float Sred[128 * 67];        // 34304 B; head doubles as At/Bt
    u16* At = (u16*)Sred;                   // [128][40] fp16 = 10240 B
    u16* Bt = At + 128 * 40;                // [64][40]  fp16 =  5120 B
    const int tid = threadIdx.x;
    const int row0 = blockIdx.x * 128;
    const int lane = tid & 63, wv = tid >> 6;
    const int wr = wv * 32;                 // wave: 32 rows x 64 cols
    const int q = lane >> 4, c0 = lane & 15;

    floatx4 acc[2][4];
#pragma unroll
    for (int m = 0; m < 2; ++m)
#pragma unroll
        for (int n = 0; n < 4; ++n) acc[m][n] = (floatx4)0.f;

    for (int kt = 0; kt < DQ; kt += 32) {
#pragma unroll
        for (int i = 0; i < 3; ++i) {
            int c = tid + i * 256;          // [0,768)
            if (c < 512) {
                int r = c >> 2, seg = c & 3;
                *(uint4*)&At[r * 40 + seg * 8] =
                    *(const uint4*)(QP + (size_t)(row0 + r) * DQ + kt + seg * 8);
            } else {
                int cb = c - 512;
                int r = cb >> 2, seg = cb & 3;
                *(uint4*)&Bt[r * 40 + seg * 8] =
                    *(const uint4*)(Mkh + (size_t)r * DQ + kt + seg * 8);
            }
        }
        __syncthreads();
        half8 af[2], bf[4];
#pragma unroll
        for (int m = 0; m < 2; ++m) af[m] = *(half8*)&At[(wr + m * 16 + c0) * 40 + q * 8];
#pragma unroll
        for (int n = 0; n < 4; ++n) bf[n] = *(half8*)&Bt[(n * 16 + c0) * 40 + q * 8];
#pragma unroll
        for (int m = 0; m < 2; ++m)
#pragma unroll
            for (int n = 0; n < 4; ++n)
                acc[m][n] = __builtin_amdgcn_mfma_f32_16x16x32_f16(af[m], bf[n], acc[m][n], 0, 0, 0);
        __syncthreads();
    }

    // dump logits to LDS: row = wr + m*16 + q*4 + r, col = n*16 + c0
#pragma unroll
    for (int m = 0; m < 2; ++m)
#pragma unroll
        for (int r4 = 0; r4 < 4; ++r4) {
            int row = wr + m * 16 + q * 4 + r4;
#pragma unroll
            for (int n = 0; n < 4; ++n)
                Sred[row * 67 + n * 16 + c0] = acc[m][n][r4];
        }
    __syncthreads();

    // row-wise softmax over 50 live cols (one thread per row)
    if (tid < 128) {
        float* s = &Sred[tid * 67];
        float mx = -3.0e38f;
#pragma unroll
        for (int m = 0; m < MM; ++m) mx = fmaxf(mx, s[m]);
        float sum = 0.f;
#pragma unroll
        for (int m = 0; m < MM; ++m) { float e = __expf(s[m] - mx); s[m] = e; sum += e; }
        float inv = 1.f / sum;
#pragma unroll
        for (int m = 0; m < MM; ++m) s[m] *= inv;
#pragma unroll
        for (int m = MM; m < 64; ++m) s[m] = 0.f;
    }
    __syncthreads();

    // packed fp16 store: 128 rows x 32 u32 (=64 halves/row)
    for (int i = tid; i < 128 * 32; i += 256) {
        int row = i >> 5, seg = i & 31;
        u32 lo = f2h(Sred[row * 67 + 2 * seg]);
        u32 hi = f2h(Sred[row * 67 + 2 * seg + 1]);
        Wh[((size_t)(row0 + row)) * 32 + seg] = lo | (hi << 16);
    }
}

// ---------------------------------------------------------------------------
// DKVMN scan v7: 1024 blocks x 64 threads — ONE INDEPENDENT WAVE per
// (batch b = bid>>2, d-slice = bid&3). No LDS, no barriers. w is fp16
// (WHS=64 u16 rows); each step's row = 7 uniform global dwordx4 loads
// (one L1 request each — no 64x LDS broadcast waste), register
// double-buffered in wA/wB (all indices unroll-static). mv[50] fp32 in
// VGPRs. e/a prefetched per WT-step tile.
// ---------------------------------------------------------------------------
__global__ __launch_bounds__(64, 1) void scan_kernel(
    const u16* __restrict__ Whb, const u32* __restrict__ EA,
    const float* __restrict__ Mv0, float* __restrict__ MvSt,
    u16* __restrict__ RDIE, int CS, int first)
{
    const int bid = blockIdx.x;
    const int b = bid >> 2;
    const int d = ((bid & 3) << 6) | threadIdx.x;

    float mv[MM];
    if (first) {
#pragma unroll
        for (int m = 0; m < MM; ++m) mv[m] = Mv0[m * DV + d];
    } else {
#pragma unroll
        for (int m = 0; m < MM; ++m) mv[m] = MvSt[((size_t)b * MM + m) * DV + d];
    }

    const u16* wrow = Whb + (size_t)b * CS * WHS;   // 128 B per row
    const u32* ep = EA + (size_t)b * CS * DV + d;
    u16* rp = RDIE + (size_t)b * CS * 384 + d;

    const int NT = CS / WT;

    u32 ea[WT];
#pragma unroll
    for (int i = 0; i < WT; ++i) ea[i] = ep[i * DV];

    u32x4 wA[7], wB[7];
#pragma unroll
    for (int i = 0; i < 7; ++i)
        wA[i] = *(const u32x4*)(wrow + i * 8);

    // one scan step: consume bank w4 (7 x u32x4 = 56 halves, 50 live)
    auto STEP = [&](const u32x4* w4, u32 eav, int t) {
        float e = h2f((u16)(eav & 0xffff));
        float a = h2f((u16)(eav >> 16));
        float r0 = 0.f, r1 = 0.f, r2 = 0.f, r3 = 0.f;
#pragma unroll
        for (int k = 0; k < 25; ++k) {
            u32 q = w4[k >> 2][k & 3];
            float wlo = h2f((u16)(q & 0xffff));
            float whi = h2f((u16)(q >> 16));
            int m = 2 * k;
            if (k & 1) {
                r2 = fmaf(wlo, mv[m], r2);
                r3 = fmaf(whi, mv[m + 1], r3);
            } else {
                r0 = fmaf(wlo, mv[m], r0);
                r1 = fmaf(whi, mv[m + 1], r1);
            }
            float t0 = a - e * mv[m];
            float t1 = a - e * mv[m + 1];
            mv[m]     = fmaf(wlo, t0, mv[m]);
            mv[m + 1] = fmaf(whi, t1, mv[m + 1]);
        }
        rp[(size_t)t * 384] = f2h((r0 + r2) + (r1 + r3));
    };

    for (int tile = 0; tile < NT; ++tile) {
        u32 ean[WT];
        const bool havenext = (tile + 1 < NT);
        if (havenext) {
#pragma unroll
            for (int i = 0; i < WT; ++i) ean[i] = ep[(WT + i) * DV];
        }
#pragma unroll
        for (int s = 0; s < WT; s += 2) {
            const int t = tile * WT + s;
            // prefetch row t+1 into wB (reads past end stay inside the
            // over-sized w allocation; values unused on the final step)
#pragma unroll
            for (int i = 0; i < 7; ++i)
                wB[i] = *(const u32x4*)(wrow + (size_t)(t + 1) * WHS + i * 8);
            STEP(wA, ea[s], t);
#pragma unroll
            for (int i = 0; i < 7; ++i)
                wA[i] = *(const u32x4*)(wrow + (size_t)(t + 2) * WHS + i * 8);
            STEP(wB, ea[s + 1], t + 1);
        }
        if (havenext) {
#pragma unroll
            for (int i = 0; i < WT; ++i) ea[i] = ean[i];
        }
        ep += WT * DV;
    }

#pragma unroll
    for (int m = 0; m < MM; ++m) MvSt[((size_t)b * MM + m) * DV + d] = mv[m];
}

// ---------------------------------------------------------------------------
// loss + outputs
// ---------------------------------------------------------------------------
__global__ __launch_bounds__(256) void loss_part(
    const float* __restrict__ P, const int* __restrict__ target,
    const float* __restrict__ pred_b, float* __restrict__ out,
    float* __restrict__ R2, int s0, int CS, int Nc)
{
    int l = blockIdx.x * 256 + threadIdx.x;
    float le = 0.f, mf = 0.f;
    if (l < Nc) {
        int n = gmap(l, s0, CS);
        float p = P[l] + pred_b[0];
        int t = target[n];
        float y = (t >= 1) ? (float)(t - 1) : 0.f;
        float sig = 1.f / (1.f + __expf(-p));
        if (t >= 1) {
            mf = 1.f;
            le = fmaxf(p, 0.f) + log1pf(__expf(-fabsf(p))) - p * y;
        }
        out[1 + n] = sig * mf;
        out[1 + NROWS + n] = y * mf;
    }
#pragma unroll
    for (int off = 32; off; off >>= 1) {
        le += __shfl_down(le, off);
        mf += __shfl_down(mf, off);
    }
    __shared__ float sl[4], sm[4];
    int wid = threadIdx.x >> 6;
    if ((threadIdx.x & 63) == 0) { sl[wid] = le; sm[wid] = mf; }
    __syncthreads();
    if (threadIdx.x == 0) {
        atomicAdd(R2, sl[0] + sl[1] + sl[2] + sl[3]);
        atomicAdd(R2 + 1, sm[0] + sm[1] + sm[2] + sm[3]);
    }
}

__global__ void loss_fin(const float* __restrict__ R2, float* __restrict__ out)
{
    out[0] = R2[0] / fmaxf(R2[1], 1.f);
}

// ---------------------------------------------------------------------------
extern "C" void kernel_launch(void* const* d_in, const int* in_sizes, int n_in,
                              void* d_out, int out_size, void* d_ws, size_t ws_size,
                              hipStream_t stream)
{
    const int* q_data       = (const int*)d_in[0];
    const int* qa_data      = (const int*)d_in[1];
    const int* target       = (const int*)d_in[2];
    const int* time_data    = (const int*)d_in[3];
    const int* attempt_data = (const int*)d_in[4];
    const int* hint_data    = (const int*)d_in[5];
    const int* hintT_data   = (const int*)d_in[6];
    const float* q_emb    = (const float*)d_in[7];
    const float* qa_emb   = (const float*)d_in[8];
    const float* time_emb = (const float*)d_in[9];
    const float* att_emb  = (const float*)d_in[10];
    const float* ht_emb   = (const float*)d_in[11];
    const float* Mk       = (const float*)d_in[12];
    const float* Mv0      = (const float*)d_in[13];
    const float* diff_W   = (const float*)d_in[14];
    const float* diff_b   = (const float*)d_in[15];
    const float* diff2_W  = (const float*)d_in[16];
    const float* diff2_b  = (const float*)d_in[17];
    const float* erase_W  = (const float*)d_in[18];
    const float* erase_b  = (const float*)d_in[19];
    const float* add_W    = (const float*)d_in[20];
    const float* add_b    = (const float*)d_in[21];
    const float* read_W   = (const float*)d_in[22];
    const float* read_b   = (const float*)d_in[23];
    const float* pred_W   = (const float*)d_in[24];
    const float* pred_b   = (const float*)d_in[25];
    float* out = (float*)d_out;
    (void)in_sizes; (void)n_in; (void)out_size;

    // Adaptive chunking over S (CS must be divisible by WT=10).
    static const int cs_opts[] = {500, 250, 100, 50, 20, 10};
    const size_t FIXED = 13107216ull + 720896ull + 10240512ull + 16384ull;
    int CS = 0;
    for (int i = 0; i < 6; ++i) {
        size_t need = (size_t)NB * cs_opts[i] * 3028ull + FIXED;
        if (need <= ws_size) { CS = cs_opts[i]; break; }
    }
    if (CS == 0) return;
    const int NCH = SQ / CS;
    const int Nc = NB * CS;

    // Workspace layout (16B-aligned sections)
    float* MvSt  = (float*)d_ws;                         // [NB*MM*DV]
    float* wbuf  = MvSt + (size_t)NB * MM * DV;          // [Nc*52] floats (fp16 rows use Nc*128B of it)
    float* bufP  = wbuf + (size_t)Nc * WSTRIDE;          // [Nc]
    float* bufR2 = bufP + Nc;                            // [4]
    u32*  EAu    = (u32*)(bufR2 + 4);                    // [Nc*256]
    u16*  Xp     = (u16*)(EAu + (size_t)Nc * 256);       // [2Nc*128]
    u16*  S3p    = Xp + (size_t)2 * Nc * 128;            // [Nc*128]
    u16*  QEp    = S3p + (size_t)Nc * 128;               // [Nc*128]
    u16*  RDIE   = QEp + (size_t)Nc * 128;               // [Nc*384]
    u16*  dWh    = RDIE + (size_t)Nc * 384;              // 16384
    u16*  d2Wh   = dWh + 16384;                          // 16384
    u16*  eWh    = d2Wh + 16384;                         // 65536
    u16*  aWh    = eWh + 65536;                          // 65536
    u16*  rWh    = aWh + 65536;                          // 196608
    u16*  qaEh   = rWh + 196608;                         // 5,120,256
    u16*  Mkh    = qaEh + 5120256;                       // 8,192 (64x128)

    // One-time weight/table conversions to fp16
    cvt16<<<16, 256, 0, stream>>>(diff_W,  dWh,  16384 / 4);
    cvt16<<<16, 256, 0, stream>>>(diff2_W, d2Wh, 16384 / 4);
    cvt16<<<64, 256, 0, stream>>>(erase_W, eWh,  65536 / 4);
    cvt16<<<64, 256, 0, stream>>>(add_W,   aWh,  65536 / 4);
    cvt16<<<192, 256, 0, stream>>>(read_W, rWh,  196608 / 4);
    cvt16<<<5001, 256, 0, stream>>>(qa_emb, qaEh, 5120256 / 4);
    mkcvt<<<8, 256, 0, stream>>>(Mk, Mkh);
    hipMemsetAsync(bufR2, 0, 4 * sizeof(float), stream);

    for (int c = 0; c < NCH; ++c) {
        const int s0 = c * CS;

        prep128<<<Nc / 8, 256, 0, stream>>>(
            q_data, time_data, attempt_data, hint_data, hintT_data,
            q_emb, time_emb, att_emb, ht_emb, Xp, S3p, QEp, s0, CS, Nc);

        // G1: [T1;T2] = tanh(lin1([X1;X2]))  (in-place Xp, 2Nc rows)
        gemm16<1><<<dim3(2 * Nc / 128, 1), 256, 0, stream>>>(
            Xp, dWh, nullptr, diff_b, nullptr, Xp, nullptr,
            nullptr, nullptr, nullptr, nullptr, nullptr, nullptr, 128, Nc, s0, CS);
        // G2: sig(lin2): rows<Nc -> tf; rows>=Nc -> x3 = qe + df*s3  (in-place)
        gemm16<2><<<dim3(2 * Nc / 128, 1), 256, 0, stream>>>(
            Xp, d2Wh, nullptr, diff2_b, nullptr, Xp, nullptr,
            QEp, S3p, nullptr, nullptr, nullptr, nullptr, 128, Nc, s0, CS);
        // G3: qp = lin1(x3) -> Xp[0:Nc); fused ie = qp + tf*te -> RDIE[:,256:)
        gemm16<3><<<dim3(Nc / 128, 1), 256, 0, stream>>>(
            Xp + (size_t)Nc * 128, dWh, nullptr, diff_b, nullptr, Xp, nullptr,
            nullptr, nullptr, time_data, time_emb, RDIE, nullptr, 128, Nc, s0, CS);
        // w = softmax(qp @ Mk^T) via MFMA, stored fp16 (WHS rows)
        wsoftmax_mfma<<<Nc / 128, 256, 0, stream>>>(Xp, Mkh, (u32*)wbuf);
        // G4: e/a gates, gather-A from fp16 qa_emb, packed (e,a) -> EAu
        gemm16<4><<<dim3(Nc / 128, 4), 256, 0, stream>>>(
            qaEh, eWh, aWh, erase_b, add_b, nullptr, nullptr,
            nullptr, nullptr, qa_data, nullptr, (u16*)EAu, nullptr, 256, Nc, s0, CS);
        // scan -> RD fp16 into RDIE[:,0:256)
        scan_kernel<<<NB * 4, 64, 0, stream>>>(
            (const u16*)wbuf, EAu, Mv0, MvSt, RDIE, CS, c == 0 ? 1 : 0);

        hipMemsetAsync(bufP, 0, (size_t)Nc * sizeof(float), stream);
        // G5: rc = tanh([rd|ie] @ read_W^T + b); pred partials -> bufP
        gemm16<5><<<dim3(Nc / 128, 4), 256, 0, stream>>>(
            RDIE, rWh, nullptr, read_b, nullptr, nullptr, bufP,
            nullptr, nullptr, nullptr, nullptr, nullptr, pred_W, 384, Nc, s0, CS);

        loss_part<<<Nc / 256, 256, 0, stream>>>(bufP, target, pred_b, out, bufR2, s0, CS, Nc);
    }

    loss_fin<<<1, 1, 0, stream>>>(bufR2, out);
}

// Round 6
// 989.184 us; speedup vs baseline: 1.2142x; 1.2142x over previous
//
#include <hip/hip_runtime.h>
#include <cstdint>
#include <cstddef>

// Problem constants
#define NB 256
#define SQ 500
#define NROWS (NB * SQ)   // 128000
#define DQ 128
#define DV 256
#define MM 50
#define FF 512
#define WSTRIDE 52        // padded w-row stride in the float layout (alloc sizing)
#define WHS 64            // fp16 w row stride (u16 units) = 128 B
#define WT 10             // scan ea-prefetch tile: steps per stage

typedef _Float16 half8 __attribute__((ext_vector_type(8)));
typedef float floatx4 __attribute__((ext_vector_type(4)));
typedef float f2 __attribute__((ext_vector_type(2)));
typedef unsigned int u32;
typedef u32 u32x4 __attribute__((ext_vector_type(4)));
typedef unsigned short u16;

__device__ __forceinline__ float4 ld4(const float* p) {
    return *reinterpret_cast<const float4*>(p);
}
__device__ __forceinline__ float sigf(float x) { return 1.f / (1.f + __expf(-x)); }
__device__ __forceinline__ float tanhfast(float x) { return 2.f / (1.f + __expf(-2.f * x)) - 1.f; }
__device__ __forceinline__ int gmap(int l, int s0, int CS) {
    int b = (unsigned)l / (unsigned)CS;
    return b * SQ + s0 + (l - b * CS);
}
__device__ __forceinline__ void st4h(u16* dst, float4 v) {
    _Float16 h0 = (_Float16)v.x, h1 = (_Float16)v.y, h2 = (_Float16)v.z, h3 = (_Float16)v.w;
    ushort4 u;
    u.x = *(u16*)&h0; u.y = *(u16*)&h1; u.z = *(u16*)&h2; u.w = *(u16*)&h3;
    *(ushort4*)dst = u;
}
__device__ __forceinline__ float h2f(u16 b) { _Float16 h; *(u16*)&h = b; return (float)h; }
__device__ __forceinline__ u16 f2h(float x) { _Float16 h = (_Float16)x; return *(u16*)&h; }

// ---------------------------------------------------------------------------
// fp32 -> fp16 conversion (vec4)
// ---------------------------------------------------------------------------
__global__ __launch_bounds__(256) void cvt16(
    const float* __restrict__ s, u16* __restrict__ d, int n4)
{
    int i = blockIdx.x * 256 + threadIdx.x;
    if (i < n4) st4h(d + 4 * (size_t)i, ld4(s + 4 * (size_t)i));
}

// ---------------------------------------------------------------------------
// Mk [50,128] fp32 -> Mkh [64,128] fp16, rows 50..63 zeroed
// ---------------------------------------------------------------------------
__global__ __launch_bounds__(256) void mkcvt(
    const float* __restrict__ Mk, u16* __restrict__ Mkh)
{
    int i = blockIdx.x * 256 + threadIdx.x;   // 2048 float4 slots
    if (i >= 64 * 32) return;
    int row = i >> 5;
    float4 v = (row < MM) ? ld4(Mk + (size_t)row * DQ + (i & 31) * 4)
                          : float4{0.f, 0.f, 0.f, 0.f};
    st4h(Mkh + 4 * (size_t)i, v);
}

// ---------------------------------------------------------------------------
// prep: Xp rows [0,Nc) = fp16(te+qe); rows [Nc,2Nc) = fp16(he+hte+ae+qe);
//       S3p = fp16(he+hte+ae); QEp = fp16(qe)
// ---------------------------------------------------------------------------
__global__ __launch_bounds__(256) void prep128(
    const int* __restrict__ q_data, const int* __restrict__ time_data,
    const int* __restrict__ attempt_data, const int* __restrict__ hint_data,
    const int* __restrict__ hintT_data,
    const float* __restrict__ q_emb, const float* __restrict__ time_emb,
    const float* __restrict__ attempt_emb, const float* __restrict__ ht_emb,
    u16* __restrict__ Xp, u16* __restrict__ S3p, u16* __restrict__ QEp,
    int s0, int CS, int Nc)
{
    int g = blockIdx.x * 256 + threadIdx.x;
    int l = g >> 5;
    int kq = (g & 31) << 2;
    if (l >= Nc) return;
    int n = gmap(l, s0, CS);
    float4 qe  = ld4(q_emb       + (size_t)q_data[n]       * DQ + kq);
    float4 te  = ld4(time_emb    + (size_t)time_data[n]    * DQ + kq);
    float4 ae  = ld4(attempt_emb + (size_t)attempt_data[n] * DQ + kq);
    float4 he  = ld4(ht_emb      + (size_t)hint_data[n]    * DQ + kq);
    float4 hte = ld4(ht_emb      + (size_t)hintT_data[n]   * DQ + kq);
    size_t off = (size_t)l * DQ + kq;
    float4 x1, s3, x2;
    x1.x = te.x + qe.x; x1.y = te.y + qe.y; x1.z = te.z + qe.z; x1.w = te.w + qe.w;
    s3.x = he.x + hte.x + ae.x; s3.y = he.y + hte.y + ae.y;
    s3.z = he.z + hte.z + ae.z; s3.w = he.w + hte.w + ae.w;
    x2.x = s3.x + qe.x; x2.y = s3.y + qe.y; x2.z = s3.z + qe.z; x2.w = s3.w + qe.w;
    st4h(Xp + off, x1);
    st4h(Xp + (size_t)Nc * DQ + off, x2);
    st4h(S3p + off, s3);
    st4h(QEp + off, qe);
}

// ---------------------------------------------------------------------------
// fp16 MFMA GEMM: Y = epi(act(A @ W^T + bias)), BM=BN=128, BK=32, 4 waves,
// wave tile 64x64 = 4x4 of v_mfma_f32_16x16x32_f16.
// MODE 1: tanh -> fp16 Yh (stride 128)               [lin1 on 2Nc rows]
// MODE 2: sig; row<Nc: tf->Yh; row>=Nc: x3=qe+v*s3 -> Yh  [lin2 batched]
// MODE 3: none; qp->Yh; fused ie=qp+tf*te -> AUX[,256:384] [lin1(X3)+ew_ie]
// MODE 4: gather A=qaE[idx]; by<2: sig->e, else tanh->a; packed u16 pairs->AUX
// MODE 5: tanh(rc); pred-partial reduce -> atomicAdd Yf    [readout+pred]
// ---------------------------------------------------------------------------
template <int MODE>
__global__ __launch_bounds__(256, 3) void gemm16(
    const u16* __restrict__ A, const u16* __restrict__ W0,
    const u16* __restrict__ W1, const float* __restrict__ b0,
    const float* __restrict__ b1, u16* __restrict__ Yh,
    float* __restrict__ Yf,
    const u16* __restrict__ QEp, const u16* __restrict__ S3p,
    const int* __restrict__ idx, const float* __restrict__ gtab,
    u16* __restrict__ AUX, const float* __restrict__ predW,
    int K, int Nc, int s0, int CS)
{
    __shared__ u16 smem[2 * 128 * 40];   // 20480 B: A-tile | B-tile (pitch 80B)
    u16* At = smem;
    u16* Bt = smem + 128 * 40;
    const int tid = threadIdx.x;
    const int row0 = blockIdx.x * 128;
    const int by = blockIdx.y;

    const u16* Wp;
    int col0;
    if constexpr (MODE == 4) { Wp = (by < 2) ? W0 : W1; col0 = (by & 1) * 128; }
    else { Wp = W0; col0 = by * 128; }
    const float* bias = (MODE == 4 && by >= 2) ? b1 : b0;

    floatx4 acc[4][4];
#pragma unroll
    for (int m = 0; m < 4; ++m)
#pragma unroll
        for (int n = 0; n < 4; ++n) acc[m][n] = (floatx4)0.f;

    const int lane = tid & 63, wv = tid >> 6;
    const int wr = (wv >> 1) * 64, wc = (wv & 1) * 64;
    const int q = lane >> 4, c0 = lane & 15;

    for (int kt = 0; kt < K; kt += 32) {
#pragma unroll
        for (int i = 0; i < 4; ++i) {
            int c = tid + i * 256;          // [0,1024)
            if (c < 512) {
                int r = c >> 2, seg = c & 3;
                const u16* src;
                if constexpr (MODE == 4) {
                    int g = idx[gmap(row0 + r, s0, CS)];
                    src = A + (size_t)g * K + kt + seg * 8;
                } else {
                    src = A + (size_t)(row0 + r) * K + kt + seg * 8;
                }
                *(uint4*)&At[r * 40 + seg * 8] = *(const uint4*)src;
            } else {
                int cb = c - 512;
                int r = cb >> 2, seg = cb & 3;
                const u16* src = Wp + (size_t)(col0 + r) * K + kt + seg * 8;
                *(uint4*)&Bt[r * 40 + seg * 8] = *(const uint4*)src;
            }
        }
        __syncthreads();
        half8 af[4], bf[4];
#pragma unroll
        for (int m = 0; m < 4; ++m) af[m] = *(half8*)&At[(wr + m * 16 + c0) * 40 + q * 8];
#pragma unroll
        for (int n = 0; n < 4; ++n) bf[n] = *(half8*)&Bt[(wc + n * 16 + c0) * 40 + q * 8];
#pragma unroll
        for (int m = 0; m < 4; ++m)
#pragma unroll
            for (int n = 0; n < 4; ++n)
                acc[m][n] = __builtin_amdgcn_mfma_f32_16x16x32_f16(af[m], bf[n], acc[m][n], 0, 0, 0);
        __syncthreads();
    }

    float bv[4];
#pragma unroll
    for (int n = 0; n < 4; ++n) bv[n] = bias[col0 + wc + n * 16 + c0];

    if constexpr (MODE == 5) {
        float pw[4];
#pragma unroll
        for (int n = 0; n < 4; ++n) pw[n] = predW[col0 + wc + n * 16 + c0];
        float* red = (float*)smem;          // [128][33] = 16896 B <= 20480
#pragma unroll
        for (int m = 0; m < 4; ++m)
#pragma unroll
            for (int r4 = 0; r4 < 4; ++r4) {
                int row = wr + m * 16 + q * 4 + r4;
                float pp = 0.f;
#pragma unroll
                for (int n = 0; n < 4; ++n)
                    pp = fmaf(tanhfast(acc[m][n][r4] + bv[n]), pw[n], pp);
                red[row * 33 + (wv & 1) * 16 + c0] = pp;
            }
        __syncthreads();
        if (tid < 128) {
            float s = 0.f;
#pragma unroll
            for (int j = 0; j < 32; ++j) s += red[tid * 33 + j];
            atomicAdd(&Yf[row0 + tid], s);
        }
    } else {
#pragma unroll
        for (int m = 0; m < 4; ++m)
#pragma unroll
            for (int r4 = 0; r4 < 4; ++r4) {
                int row = row0 + wr + m * 16 + q * 4 + r4;
#pragma unroll
                for (int n = 0; n < 4; ++n) {
                    int col = col0 + wc + n * 16 + c0;
                    float v = acc[m][n][r4] + bv[n];
                    if constexpr (MODE == 1) {
                        Yh[(size_t)row * 128 + col] = f2h(tanhfast(v));
                    } else if constexpr (MODE == 2) {
                        v = sigf(v);
                        if (row < Nc) {
                            Yh[(size_t)row * 128 + col] = f2h(v);
                        } else {
                            size_t o = (size_t)(row - Nc) * 128 + col;
                            float qe = h2f(QEp[o]), s3 = h2f(S3p[o]);
                            Yh[(size_t)row * 128 + col] = f2h(fmaf(v, s3, qe));
                        }
                    } else if constexpr (MODE == 3) {
                        size_t o = (size_t)row * 128 + col;
                        float tf = h2f(Yh[o]);   // read tf BEFORE overwriting with qp
                        float te = gtab[(size_t)idx[gmap(row, s0, CS)] * 128 + col];
                        AUX[(size_t)row * 384 + 256 + col] = f2h(fmaf(tf, te, v));
                        Yh[o] = f2h(v);
                    } else { // MODE 4
                        bool isE = (by < 2);
                        v = isE ? sigf(v) : tanhfast(v);
                        AUX[((size_t)row * 256 + col) * 2 + (isE ? 0 : 1)] = f2h(v);
                    }
                }
            }
    }
}

// ---------------------------------------------------------------------------
// w = softmax(qp @ Mk^T) via MFMA. Block: 128 rows x 64 cols (50 live).
// Logits -> LDS (pitch 67), row softmax, then packed fp16 store to Wh
// (stride WHS=64 u16 = 128 B per row; cols 50..63 zeroed).
// ---------------------------------------------------------------------------
__global__ __launch_bounds__(256) void wsoftmax_mfma(
    const u16* __restrict__ QP, const u16* __restrict__ Mkh,
    u32* __restrict__ Wh)
{
    __shared__ float Sred[128 * 67];        // 34304 B; head doubles as At/Bt
    u16* At = (u16*)Sred;                   // [128][40] fp16 = 10240 B
    u16* Bt = At + 128 * 40;                // [64][40]  fp16 =  5120 B
    const int tid = threadIdx.x;
    const int row0 = blockIdx.x * 128;
    const int lane = tid & 63, wv = tid >> 6;
    const int wr = wv * 32;                 // wave: 32 rows x 64 cols
    const int q = lane >> 4, c0 = lane & 15;

    floatx4 acc[2][4];
#pragma unroll
    for (int m = 0; m < 2; ++m)
#pragma unroll
        for (int n = 0; n < 4; ++n) acc[m][n] = (floatx4)0.f;

    for (int kt = 0; kt < DQ; kt += 32) {
#pragma unroll
        for (int i = 0; i < 3; ++i) {
            int c = tid + i * 256;          // [0,768)
            if (c < 512) {
                int r = c >> 2, seg = c & 3;
                *(uint4*)&At[r * 40 + seg * 8] =
                    *(const uint4*)(QP + (size_t)(row0 + r) * DQ + kt + seg * 8);
            } else {
                int cb = c - 512;
                int r = cb >> 2, seg = cb & 3;
                *(uint4*)&Bt[r * 40 + seg * 8] =
                    *(const uint4*)(Mkh + (size_t)r * DQ + kt + seg * 8);
            }
        }
        __syncthreads();
        half8 af[2], bf[4];
#pragma unroll
        for (int m = 0; m < 2; ++m) af[m] = *(half8*)&At[(wr + m * 16 + c0) * 40 + q * 8];
#pragma unroll
        for (int n = 0; n < 4; ++n) bf[n] = *(half8*)&Bt[(n * 16 + c0) * 40 + q * 8];
#pragma unroll
        for (int m = 0; m < 2; ++m)
#pragma unroll
            for (int n = 0; n < 4; ++n)
                acc[m][n] = __builtin_amdgcn_mfma_f32_16x16x32_f16(af[m], bf[n], acc[m][n], 0, 0, 0);
        __syncthreads();
    }

    // dump logits to LDS: row = wr + m*16 + q*4 + r, col = n*16 + c0
#pragma unroll
    for (int m = 0; m < 2; ++m)
#pragma unroll
        for (int r4 = 0; r4 < 4; ++r4) {
            int row = wr + m * 16 + q * 4 + r4;
#pragma unroll
            for (int n = 0; n < 4; ++n)
                Sred[row * 67 + n * 16 + c0] = acc[m][n][r4];
        }
    __syncthreads();

    // row-wise softmax over 50 live cols (one thread per row)
    if (tid < 128) {
        float* s = &Sred[tid * 67];
        float mx = -3.0e38f;
#pragma unroll
        for (int m = 0; m < MM; ++m) mx = fmaxf(mx, s[m]);
        float sum = 0.f;
#pragma unroll
        for (int m = 0; m < MM; ++m) { float e = __expf(s[m] - mx); s[m] = e; sum += e; }
        float inv = 1.f / sum;
#pragma unroll
        for (int m = 0; m < MM; ++m) s[m] *= inv;
#pragma unroll
        for (int m = MM; m < 64; ++m) s[m] = 0.f;
    }
    __syncthreads();

    // packed fp16 store: 128 rows x 32 u32 (=64 halves/row)
    for (int i = tid; i < 128 * 32; i += 256) {
        int row = i >> 5, seg = i & 31;
        u32 lo = f2h(Sred[row * 67 + 2 * seg]);
        u32 hi = f2h(Sred[row * 67 + 2 * seg + 1]);
        Wh[((size_t)(row0 + row)) * 32 + seg] = lo | (hi << 16);
    }
}

// ---------------------------------------------------------------------------
// DKVMN scan v8: 1024 blocks x 64 threads — one independent wave per
// (batch b = bid>>2, d-slice = bid&3). No LDS, no barriers.
// KEY FIX vs v7: the w row base pointer is laundered through
// __shfl(threadIdx.x, 0) (runtime 0, but ds_bpermute results are marked
// DIVERGENT by LLVM's uniformity analysis) so the 7 dwordx4 loads per row
// compile to VMEM global_load_dwordx4 (per-lane addr, HW-coalesced to one
// L2 request/wave, compiler-pipelined with counted vmcnt) instead of the
// serialized SMEM s_load path (R4: SGPR=80, 233 us). Register double-
// buffered banks wA/wB (depth 2). Math in packed f2 (mv[25] f2): per pair
// 2 cvt + 3 pk-FMA -> ~150 VALU inst/step.
// ---------------------------------------------------------------------------
__global__ __launch_bounds__(64, 1) void scan_kernel(
    const u16* __restrict__ Whb, const u32* __restrict__ EA,
    const float* __restrict__ Mv0, float* __restrict__ MvSt,
    u16* __restrict__ RDIE, int CS, int first)
{
    const int bid = blockIdx.x;
    const int b = bid >> 2;
    const int d = ((bid & 3) << 6) | threadIdx.x;

    f2 mv[25];
    if (first) {
#pragma unroll
        for (int j = 0; j < 25; ++j) {
            mv[j].x = Mv0[(2 * j) * DV + d];
            mv[j].y = Mv0[(2 * j + 1) * DV + d];
        }
    } else {
#pragma unroll
        for (int j = 0; j < 25; ++j) {
            mv[j].x = MvSt[((size_t)b * MM + 2 * j) * DV + d];
            mv[j].y = MvSt[((size_t)b * MM + 2 * j + 1) * DV + d];
        }
    }

    // divergence-laundered base: value 0, but defeats scalarization
    const int zdiv = __shfl((int)threadIdx.x, 0);
    const u16* wrow = Whb + (size_t)b * CS * WHS + zdiv;   // 128 B per row
    const u32* ep = EA + (size_t)b * CS * DV + d;
    u16* rp = RDIE + (size_t)b * CS * 384 + d;

    const int NT = CS / WT;

    u32 ea[WT];
#pragma unroll
    for (int i = 0; i < WT; ++i) ea[i] = ep[i * DV];

    u32x4 wA[7], wB[7];
#pragma unroll
    for (int i = 0; i < 7; ++i)
        wA[i] = *(const u32x4*)(wrow + i * 8);

    // one scan step: consume bank w4 (7 x u32x4 = 56 halves, 50 live)
    auto STEP = [&](const u32x4* w4, u32 eav, int t) {
        float e = h2f((u16)(eav & 0xffff));
        float a = h2f((u16)(eav >> 16));
        f2 e2; e2.x = e; e2.y = e;
        f2 a2; a2.x = a; a2.y = a;
        f2 r0 = (f2)0.f, r1 = (f2)0.f, r2 = (f2)0.f, r3 = (f2)0.f;
#pragma unroll
        for (int k = 0; k < 25; ++k) {
            u32 q = w4[k >> 2][k & 3];
            f2 w2;
            w2.x = h2f((u16)(q & 0xffff));
            w2.y = h2f((u16)(q >> 16));
            if ((k & 3) == 0)      r0 += w2 * mv[k];
            else if ((k & 3) == 1) r1 += w2 * mv[k];
            else if ((k & 3) == 2) r2 += w2 * mv[k];
            else                   r3 += w2 * mv[k];
            f2 tt = a2 - e2 * mv[k];
            mv[k] += w2 * tt;
        }
        f2 rs = (r0 + r1) + (r2 + r3);
        rp[(size_t)t * 384] = f2h(rs.x + rs.y);
    };

    for (int tile = 0; tile < NT; ++tile) {
        u32 ean[WT];
        const bool havenext = (tile + 1 < NT);
        if (havenext) {
#pragma unroll
            for (int i = 0; i < WT; ++i) ean[i] = ep[(WT + i) * DV];
        }
#pragma unroll
        for (int s = 0; s < WT; s += 2) {
            const int t = tile * WT + s;
            // prefetch row t+1 into wB (tail rows read allocation slack)
#pragma unroll
            for (int i = 0; i < 7; ++i)
                wB[i] = *(const u32x4*)(wrow + (size_t)(t + 1) * WHS + i * 8);
            STEP(wA, ea[s], t);
#pragma unroll
            for (int i = 0; i < 7; ++i)
                wA[i] = *(const u32x4*)(wrow + (size_t)(t + 2) * WHS + i * 8);
            STEP(wB, ea[s + 1], t + 1);
        }
        if (havenext) {
#pragma unroll
            for (int i = 0; i < WT; ++i) ea[i] = ean[i];
        }
        ep += WT * DV;
    }

#pragma unroll
    for (int j = 0; j < 25; ++j) {
        MvSt[((size_t)b * MM + 2 * j) * DV + d]     = mv[j].x;
        MvSt[((size_t)b * MM + 2 * j + 1) * DV + d] = mv[j].y;
    }
}

// ---------------------------------------------------------------------------
// loss + outputs
// ---------------------------------------------------------------------------
__global__ __launch_bounds__(256) void loss_part(
    const float* __restrict__ P, const int* __restrict__ target,
    const float* __restrict__ pred_b, float* __restrict__ out,
    float* __restrict__ R2, int s0, int CS, int Nc)
{
    int l = blockIdx.x * 256 + threadIdx.x;
    float le = 0.f, mf = 0.f;
    if (l < Nc) {
        int n = gmap(l, s0, CS);
        float p = P[l] + pred_b[0];
        int t = target[n];
        float y = (t >= 1) ? (float)(t - 1) : 0.f;
        float sig = 1.f / (1.f + __expf(-p));
        if (t >= 1) {
            mf = 1.f;
            le = fmaxf(p, 0.f) + log1pf(__expf(-fabsf(p))) - p * y;
        }
        out[1 + n] = sig * mf;
        out[1 + NROWS + n] = y * mf;
    }
#pragma unroll
    for (int off = 32; off; off >>= 1) {
        le += __shfl_down(le, off);
        mf += __shfl_down(mf, off);
    }
    __shared__ float sl[4], sm[4];
    int wid = threadIdx.x >> 6;
    if ((threadIdx.x & 63) == 0) { sl[wid] = le; sm[wid] = mf; }
    __syncthreads();
    if (threadIdx.x == 0) {
        atomicAdd(R2, sl[0] + sl[1] + sl[2] + sl[3]);
        atomicAdd(R2 + 1, sm[0] + sm[1] + sm[2] + sm[3]);
    }
}

__global__ void loss_fin(const float* __restrict__ R2, float* __restrict__ out)
{
    out[0] = R2[0] / fmaxf(R2[1], 1.f);
}

// ---------------------------------------------------------------------------
extern "C" void kernel_launch(void* const* d_in, const int* in_sizes, int n_in,
                              void* d_out, int out_size, void* d_ws, size_t ws_size,
                              hipStream_t stream)
{
    const int* q_data       = (const int*)d_in[0];
    const int* qa_data      = (const int*)d_in[1];
    const int* target       = (const int*)d_in[2];
    const int* time_data    = (const int*)d_in[3];
    const int* attempt_data = (const int*)d_in[4];
    const int* hint_data    = (const int*)d_in[5];
    const int* hintT_data   = (const int*)d_in[6];
    const float* q_emb    = (const float*)d_in[7];
    const float* qa_emb   = (const float*)d_in[8];
    const float* time_emb = (const float*)d_in[9];
    const float* att_emb  = (const float*)d_in[10];
    const float* ht_emb   = (const float*)d_in[11];
    const float* Mk       = (const float*)d_in[12];
    const float* Mv0      = (const float*)d_in[13];
    const float* diff_W   = (const float*)d_in[14];
    const float* diff_b   = (const float*)d_in[15];
    const float* diff2_W  = (const float*)d_in[16];
    const float* diff2_b  = (const float*)d_in[17];
    const float* erase_W  = (const float*)d_in[18];
    const float* erase_b  = (const float*)d_in[19];
    const float* add_W    = (const float*)d_in[20];
    const float* add_b    = (const float*)d_in[21];
    const float* read_W   = (const float*)d_in[22];
    const float* read_b   = (const float*)d_in[23];
    const float* pred_W   = (const float*)d_in[24];
    const float* pred_b   = (const float*)d_in[25];
    float* out = (float*)d_out;
    (void)in_sizes; (void)n_in; (void)out_size;

    // Adaptive chunking over S (CS must be divisible by WT=10).
    static const int cs_opts[] = {500, 250, 100, 50, 20, 10};
    const size_t FIXED = 13107216ull + 720896ull + 10240512ull + 16384ull;
    int CS = 0;
    for (int i = 0; i < 6; ++i) {
        size_t need = (size_t)NB * cs_opts[i] * 3028ull + FIXED;
        if (need <= ws_size) { CS = cs_opts[i]; break; }
    }
    if (CS == 0) return;
    const int NCH = SQ / CS;
    const int Nc = NB * CS;

    // Workspace layout (16B-aligned sections)
    float* MvSt  = (float*)d_ws;                         // [NB*MM*DV]
    float* wbuf  = MvSt + (size_t)NB * MM * DV;          // [Nc*52] floats (fp16 rows use Nc*128B of it)
    float* bufP  = wbuf + (size_t)Nc * WSTRIDE;          // [Nc]
    float* bufR2 = bufP + Nc;                            // [4]
    u32*  EAu    = (u32*)(bufR2 + 4);                    // [Nc*256]
    u16*  Xp     = (u16*)(EAu + (size_t)Nc * 256);       // [2Nc*128]
    u16*  S3p    = Xp + (size_t)2 * Nc * 128;            // [Nc*128]
    u16*  QEp    = S3p + (size_t)Nc * 128;               // [Nc*128]
    u16*  RDIE   = QEp + (size_t)Nc * 128;               // [Nc*384]
    u16*  dWh    = RDIE + (size_t)Nc * 384;              // 16384
    u16*  d2Wh   = dWh + 16384;                          // 16384
    u16*  eWh    = d2Wh + 16384;                         // 65536
    u16*  aWh    = eWh + 65536;                          // 65536
    u16*  rWh    = aWh + 65536;                          // 196608
    u16*  qaEh   = rWh + 196608;                         // 5,120,256
    u16*  Mkh    = qaEh + 5120256;                       // 8,192 (64x128)

    // One-time weight/table conversions to fp16
    cvt16<<<16, 256, 0, stream>>>(diff_W,  dWh,  16384 / 4);
    cvt16<<<16, 256, 0, stream>>>(diff2_W, d2Wh, 16384 / 4);
    cvt16<<<64, 256, 0, stream>>>(erase_W, eWh,  65536 / 4);
    cvt16<<<64, 256, 0, stream>>>(add_W,   aWh,  65536 / 4);
    cvt16<<<192, 256, 0, stream>>>(read_W, rWh,  196608 / 4);
    cvt16<<<5001, 256, 0, stream>>>(qa_emb, qaEh, 5120256 / 4);
    mkcvt<<<8, 256, 0, stream>>>(Mk, Mkh);
    hipMemsetAsync(bufR2, 0, 4 * sizeof(float), stream);

    for (int c = 0; c < NCH; ++c) {
        const int s0 = c * CS;

        prep128<<<Nc / 8, 256, 0, stream>>>(
            q_data, time_data, attempt_data, hint_data, hintT_data,
            q_emb, time_emb, att_emb, ht_emb, Xp, S3p, QEp, s0, CS, Nc);

        // G1: [T1;T2] = tanh(lin1([X1;X2]))  (in-place Xp, 2Nc rows)
        gemm16<1><<<dim3(2 * Nc / 128, 1), 256, 0, stream>>>(
            Xp, dWh, nullptr, diff_b, nullptr, Xp, nullptr,
            nullptr, nullptr, nullptr, nullptr, nullptr, nullptr, 128, Nc, s0, CS);
        // G2: sig(lin2): rows<Nc -> tf; rows>=Nc -> x3 = qe + df*s3  (in-place)
        gemm16<2><<<dim3(2 * Nc / 128, 1), 256, 0, stream>>>(
            Xp, d2Wh, nullptr, diff2_b, nullptr, Xp, nullptr,
            QEp, S3p, nullptr, nullptr, nullptr, nullptr, 128, Nc, s0, CS);
        // G3: qp = lin1(x3) -> Xp[0:Nc); fused ie = qp + tf*te -> RDIE[:,256:)
        gemm16<3><<<dim3(Nc / 128, 1), 256, 0, stream>>>(
            Xp + (size_t)Nc * 128, dWh, nullptr, diff_b, nullptr, Xp, nullptr,
            nullptr, nullptr, time_data, time_emb, RDIE, nullptr, 128, Nc, s0, CS);
        // w = softmax(qp @ Mk^T) via MFMA, stored fp16 (WHS rows)
        wsoftmax_mfma<<<Nc / 128, 256, 0, stream>>>(Xp, Mkh, (u32*)wbuf);
        // G4: e/a gates, gather-A from fp16 qa_emb, packed (e,a) -> EAu
        gemm16<4><<<dim3(Nc / 128, 4), 256, 0, stream>>>(
            qaEh, eWh, aWh, erase_b, add_b, nullptr, nullptr,
            nullptr, nullptr, qa_data, nullptr, (u16*)EAu, nullptr, 256, Nc, s0, CS);
        // scan -> RD fp16 into RDIE[:,0:256)
        scan_kernel<<<NB * 4, 64, 0, stream>>>(
            (const u16*)wbuf, EAu, Mv0, MvSt, RDIE, CS, c == 0 ? 1 : 0);

        hipMemsetAsync(bufP, 0, (size_t)Nc * sizeof(float), stream);
        // G5: rc = tanh([rd|ie] @ read_W^T + b); pred partials -> bufP
        gemm16<5><<<dim3(Nc / 128, 4), 256, 0, stream>>>(
            RDIE, rWh, nullptr, read_b, nullptr, nullptr, bufP,
            nullptr, nullptr, nullptr, nullptr, nullptr, pred_W, 384, Nc, s0, CS);

        loss_part<<<Nc / 256, 256, 0, stream>>>(bufP, target, pred_b, out, bufR2, s0, CS, Nc);
    }

    loss_fin<<<1, 1, 0, stream>>>(bufR2, out);
}

// Round 7
// 722.457 us; speedup vs baseline: 1.6625x; 1.3692x over previous
//
#include <hip/hip_runtime.h>
#include <cstdint>
#include <cstddef>

// Problem constants
#define NB 256
#define SQ 500
#define NROWS (NB * SQ)   // 128000
#define DQ 128
#define DV 256
#define MM 50
#define FF 512
#define NQA 20096         // padded distinct qa indices (2*NQ+1 = 20001 -> 157*128)
#define WSTRIDE 52        // padded w-row stride (16B aligned)
#define WT 10             // scan LDS tile: steps per stage

typedef _Float16 half8 __attribute__((ext_vector_type(8)));
typedef float floatx4 __attribute__((ext_vector_type(4)));
typedef float f2 __attribute__((ext_vector_type(2)));
typedef unsigned int u32;
typedef unsigned short u16;

__device__ __forceinline__ float4 ld4(const float* p) {
    return *reinterpret_cast<const float4*>(p);
}
__device__ __forceinline__ float sigf(float x) { return 1.f / (1.f + __expf(-x)); }
__device__ __forceinline__ float tanhfast(float x) { return 2.f / (1.f + __expf(-2.f * x)) - 1.f; }
__device__ __forceinline__ int gmap(int l, int s0, int CS) {
    int b = (unsigned)l / (unsigned)CS;
    return b * SQ + s0 + (l - b * CS);
}
__device__ __forceinline__ void st4h(u16* dst, float4 v) {
    _Float16 h0 = (_Float16)v.x, h1 = (_Float16)v.y, h2 = (_Float16)v.z, h3 = (_Float16)v.w;
    ushort4 u;
    u.x = *(u16*)&h0; u.y = *(u16*)&h1; u.z = *(u16*)&h2; u.w = *(u16*)&h3;
    *(ushort4*)dst = u;
}
__device__ __forceinline__ float h2f(u16 b) { _Float16 h; *(u16*)&h = b; return (float)h; }
__device__ __forceinline__ u16 f2h(float x) { _Float16 h = (_Float16)x; return *(u16*)&h; }

// ---------------------------------------------------------------------------
// fp32 -> fp16 conversion (vec4)
// ---------------------------------------------------------------------------
__global__ __launch_bounds__(256) void cvt16(
    const float* __restrict__ s, u16* __restrict__ d, int n4)
{
    int i = blockIdx.x * 256 + threadIdx.x;
    if (i < n4) st4h(d + 4 * (size_t)i, ld4(s + 4 * (size_t)i));
}

// ---------------------------------------------------------------------------
// Mk [50,128] fp32 -> Mkh [64,128] fp16, rows 50..63 zeroed
// ---------------------------------------------------------------------------
__global__ __launch_bounds__(256) void mkcvt(
    const float* __restrict__ Mk, u16* __restrict__ Mkh)
{
    int i = blockIdx.x * 256 + threadIdx.x;   // 2048 float4 slots
    if (i >= 64 * 32) return;
    int row = i >> 5;
    float4 v = (row < MM) ? ld4(Mk + (size_t)row * DQ + (i & 31) * 4)
                          : float4{0.f, 0.f, 0.f, 0.f};
    st4h(Mkh + 4 * (size_t)i, v);
}

// ---------------------------------------------------------------------------
// prep: Xp rows [0,Nc) = fp16(te+qe); rows [Nc,2Nc) = fp16(he+hte+ae+qe);
//       S3p = fp16(he+hte+ae); QEp = fp16(qe)
// ---------------------------------------------------------------------------
__global__ __launch_bounds__(256) void prep128(
    const int* __restrict__ q_data, const int* __restrict__ time_data,
    const int* __restrict__ attempt_data, const int* __restrict__ hint_data,
    const int* __restrict__ hintT_data,
    const float* __restrict__ q_emb, const float* __restrict__ time_emb,
    const float* __restrict__ attempt_emb, const float* __restrict__ ht_emb,
    u16* __restrict__ Xp, u16* __restrict__ S3p, u16* __restrict__ QEp,
    int s0, int CS, int Nc)
{
    int g = blockIdx.x * 256 + threadIdx.x;
    int l = g >> 5;
    int kq = (g & 31) << 2;
    if (l >= Nc) return;
    int n = gmap(l, s0, CS);
    float4 qe  = ld4(q_emb       + (size_t)q_data[n]       * DQ + kq);
    float4 te  = ld4(time_emb    + (size_t)time_data[n]    * DQ + kq);
    float4 ae  = ld4(attempt_emb + (size_t)attempt_data[n] * DQ + kq);
    float4 he  = ld4(ht_emb      + (size_t)hint_data[n]    * DQ + kq);
    float4 hte = ld4(ht_emb      + (size_t)hintT_data[n]   * DQ + kq);
    size_t off = (size_t)l * DQ + kq;
    float4 x1, s3, x2;
    x1.x = te.x + qe.x; x1.y = te.y + qe.y; x1.z = te.z + qe.z; x1.w = te.w + qe.w;
    s3.x = he.x + hte.x + ae.x; s3.y = he.y + hte.y + ae.y;
    s3.z = he.z + hte.z + ae.z; s3.w = he.w + hte.w + ae.w;
    x2.x = s3.x + qe.x; x2.y = s3.y + qe.y; x2.z = s3.z + qe.z; x2.w = s3.w + qe.w;
    st4h(Xp + off, x1);
    st4h(Xp + (size_t)Nc * DQ + off, x2);
    st4h(S3p + off, s3);
    st4h(QEp + off, qe);
}

// ---------------------------------------------------------------------------
// fp16 MFMA GEMM: Y = epi(act(A @ W^T + bias)), BM=BN=128, BK=32, 4 waves,
// wave tile 64x64 = 4x4 of v_mfma_f32_16x16x32_f16.
// MODE 1: tanh -> fp16 Yh (stride 128)               [lin1 on 2Nc rows]
// MODE 2: sig; row<Nc: tf->Yh; row>=Nc: x3=qe+v*s3 -> Yh  [lin2 batched]
// MODE 3: none; qp->Yh; fused ie=qp+tf*te -> AUX[,256:384] [lin1(X3)+ew_ie]
// MODE 4: e/a TABLE build over qa indices (A row = index, NO gather):
//         by<2: sig->e, else tanh->a; packed u16 pairs -> AUX
// MODE 5: tanh(rc); pred-partial reduce -> atomicAdd Yf    [readout+pred]
// ---------------------------------------------------------------------------
template <int MODE>
__global__ __launch_bounds__(256, 3) void gemm16(
    const u16* __restrict__ A, const u16* __restrict__ W0,
    const u16* __restrict__ W1, const float* __restrict__ b0,
    const float* __restrict__ b1, u16* __restrict__ Yh,
    float* __restrict__ Yf,
    const u16* __restrict__ QEp, const u16* __restrict__ S3p,
    const int* __restrict__ idx, const float* __restrict__ gtab,
    u16* __restrict__ AUX, const float* __restrict__ predW,
    int K, int Nc, int s0, int CS)
{
    __shared__ u16 smem[2 * 128 * 40];   // 20480 B: A-tile | B-tile (pitch 80B)
    u16* At = smem;
    u16* Bt = smem + 128 * 40;
    const int tid = threadIdx.x;
    const int row0 = blockIdx.x * 128;
    const int by = blockIdx.y;

    const u16* Wp;
    int col0;
    if constexpr (MODE == 4) { Wp = (by < 2) ? W0 : W1; col0 = (by & 1) * 128; }
    else { Wp = W0; col0 = by * 128; }
    const float* bias = (MODE == 4 && by >= 2) ? b1 : b0;

    floatx4 acc[4][4];
#pragma unroll
    for (int m = 0; m < 4; ++m)
#pragma unroll
        for (int n = 0; n < 4; ++n) acc[m][n] = (floatx4)0.f;

    const int lane = tid & 63, wv = tid >> 6;
    const int wr = (wv >> 1) * 64, wc = (wv & 1) * 64;
    const int q = lane >> 4, c0 = lane & 15;

    for (int kt = 0; kt < K; kt += 32) {
#pragma unroll
        for (int i = 0; i < 4; ++i) {
            int c = tid + i * 256;          // [0,1024)
            if (c < 512) {
                int r = c >> 2, seg = c & 3;
                const u16* src = A + (size_t)(row0 + r) * K + kt + seg * 8;
                *(uint4*)&At[r * 40 + seg * 8] = *(const uint4*)src;
            } else {
                int cb = c - 512;
                int r = cb >> 2, seg = cb & 3;
                const u16* src = Wp + (size_t)(col0 + r) * K + kt + seg * 8;
                *(uint4*)&Bt[r * 40 + seg * 8] = *(const uint4*)src;
            }
        }
        __syncthreads();
        half8 af[4], bf[4];
#pragma unroll
        for (int m = 0; m < 4; ++m) af[m] = *(half8*)&At[(wr + m * 16 + c0) * 40 + q * 8];
#pragma unroll
        for (int n = 0; n < 4; ++n) bf[n] = *(half8*)&Bt[(wc + n * 16 + c0) * 40 + q * 8];
#pragma unroll
        for (int m = 0; m < 4; ++m)
#pragma unroll
            for (int n = 0; n < 4; ++n)
                acc[m][n] = __builtin_amdgcn_mfma_f32_16x16x32_f16(af[m], bf[n], acc[m][n], 0, 0, 0);
        __syncthreads();
    }

    float bv[4];
#pragma unroll
    for (int n = 0; n < 4; ++n) bv[n] = bias[col0 + wc + n * 16 + c0];

    if constexpr (MODE == 5) {
        float pw[4];
#pragma unroll
        for (int n = 0; n < 4; ++n) pw[n] = predW[col0 + wc + n * 16 + c0];
        float* red = (float*)smem;          // [128][33] = 16896 B <= 20480
#pragma unroll
        for (int m = 0; m < 4; ++m)
#pragma unroll
            for (int r4 = 0; r4 < 4; ++r4) {
                int row = wr + m * 16 + q * 4 + r4;
                float pp = 0.f;
#pragma unroll
                for (int n = 0; n < 4; ++n)
                    pp = fmaf(tanhfast(acc[m][n][r4] + bv[n]), pw[n], pp);
                red[row * 33 + (wv & 1) * 16 + c0] = pp;
            }
        __syncthreads();
        if (tid < 128) {
            float s = 0.f;
#pragma unroll
            for (int j = 0; j < 32; ++j) s += red[tid * 33 + j];
            atomicAdd(&Yf[row0 + tid], s);
        }
    } else {
#pragma unroll
        for (int m = 0; m < 4; ++m)
#pragma unroll
            for (int r4 = 0; r4 < 4; ++r4) {
                int row = row0 + wr + m * 16 + q * 4 + r4;
#pragma unroll
                for (int n = 0; n < 4; ++n) {
                    int col = col0 + wc + n * 16 + c0;
                    float v = acc[m][n][r4] + bv[n];
                    if constexpr (MODE == 1) {
                        Yh[(size_t)row * 128 + col] = f2h(tanhfast(v));
                    } else if constexpr (MODE == 2) {
                        v = sigf(v);
                        if (row < Nc) {
                            Yh[(size_t)row * 128 + col] = f2h(v);
                        } else {
                            size_t o = (size_t)(row - Nc) * 128 + col;
                            float qe = h2f(QEp[o]), s3 = h2f(S3p[o]);
                            Yh[(size_t)row * 128 + col] = f2h(fmaf(v, s3, qe));
                        }
                    } else if constexpr (MODE == 3) {
                        size_t o = (size_t)row * 128 + col;
                        float tf = h2f(Yh[o]);   // read tf BEFORE overwriting with qp
                        float te = gtab[(size_t)idx[gmap(row, s0, CS)] * 128 + col];
                        AUX[(size_t)row * 384 + 256 + col] = f2h(fmaf(tf, te, v));
                        Yh[o] = f2h(v);
                    } else { // MODE 4
                        bool isE = (by < 2);
                        v = isE ? sigf(v) : tanhfast(v);
                        AUX[((size_t)row * 256 + col) * 2 + (isE ? 0 : 1)] = f2h(v);
                    }
                }
            }
    }
}

// ---------------------------------------------------------------------------
// w = softmax(qp @ Mk^T) via MFMA. Block: 128 rows x 64 cols (50 live).
// Logits -> LDS (pitch 67: conflict-free column reads), row softmax,
// coalesced float4 store to Wb (stride WSTRIDE).
// ---------------------------------------------------------------------------
__global__ __launch_bounds__(256) void wsoftmax_mfma(
    const u16* __restrict__ QP, const u16* __restrict__ Mkh,
    float* __restrict__ Wb)
{
    __shared__ float Sred[128 * 67];        // 34304 B; head doubles as At/Bt
    u16* At = (u16*)Sred;                   // [128][40] fp16 = 10240 B
    u16* Bt = At + 128 * 40;                // [64][40]  fp16 =  5120 B
    const int tid = threadIdx.x;
    const int row0 = blockIdx.x * 128;
    const int lane = tid & 63, wv = tid >> 6;
    const int wr = wv * 32;                 // wave: 32 rows x 64 cols
    const int q = lane >> 4, c0 = lane & 15;

    floatx4 acc[2][4];
#pragma unroll
    for (int m = 0; m < 2; ++m)
#pragma unroll
        for (int n = 0; n < 4; ++n) acc[m][n] = (floatx4)0.f;

    for (int kt = 0; kt < DQ; kt += 32) {
#pragma unroll
        for (int i = 0; i < 3; ++i) {
            int c = tid + i * 256;          // [0,768)
            if (c < 512) {
                int r = c >> 2, seg = c & 3;
                *(uint4*)&At[r * 40 + seg * 8] =
                    *(const uint4*)(QP + (size_t)(row0 + r) * DQ + kt + seg * 8);
            } else {
                int cb = c - 512;
                int r = cb >> 2, seg = cb & 3;
                *(uint4*)&Bt[r * 40 + seg * 8] =
                    *(const uint4*)(Mkh + (size_t)r * DQ + kt + seg * 8);
            }
        }
        __syncthreads();
        half8 af[2], bf[4];
#pragma unroll
        for (int m = 0; m < 2; ++m) af[m] = *(half8*)&At[(wr + m * 16 + c0) * 40 + q * 8];
#pragma unroll
        for (int n = 0; n < 4; ++n) bf[n] = *(half8*)&Bt[(n * 16 + c0) * 40 + q * 8];
#pragma unroll
        for (int m = 0; m < 2; ++m)
#pragma unroll
            for (int n = 0; n < 4; ++n)
                acc[m][n] = __builtin_amdgcn_mfma_f32_16x16x32_f16(af[m], bf[n], acc[m][n], 0, 0, 0);
        __syncthreads();
    }

    // dump logits to LDS: row = wr + m*16 + q*4 + r, col = n*16 + c0
#pragma unroll
    for (int m = 0; m < 2; ++m)
#pragma unroll
        for (int r4 = 0; r4 < 4; ++r4) {
            int row = wr + m * 16 + q * 4 + r4;
#pragma unroll
            for (int n = 0; n < 4; ++n)
                Sred[row * 67 + n * 16 + c0] = acc[m][n][r4];
        }
    __syncthreads();

    // row-wise softmax over 50 live cols (one thread per row)
    if (tid < 128) {
        float* s = &Sred[tid * 67];
        float mx = -3.0e38f;
#pragma unroll
        for (int m = 0; m < MM; ++m) mx = fmaxf(mx, s[m]);
        float sum = 0.f;
#pragma unroll
        for (int m = 0; m < MM; ++m) { float e = __expf(s[m] - mx); s[m] = e; sum += e; }
        float inv = 1.f / sum;
#pragma unroll
        for (int m = 0; m < MM; ++m) s[m] *= inv;
        s[50] = 0.f; s[51] = 0.f;
    }
    __syncthreads();

    // coalesced store: 128 rows x 13 float4
    for (int i = tid; i < 128 * 13; i += 256) {
        int row = i / 13, seg = i - row * 13;
        float4 v;
        v.x = Sred[row * 67 + seg * 4 + 0];
        v.y = Sred[row * 67 + seg * 4 + 1];
        v.z = Sred[row * 67 + seg * 4 + 2];
        v.w = Sred[row * 67 + seg * 4 + 3];
        *(float4*)(Wb + (size_t)(row0 + row) * WSTRIDE + seg * 4) = v;
    }
}

// ---------------------------------------------------------------------------
// DKVMN scan v9 = v6 (best measured: 99us) + ea gathered from the per-qa-
// index table EAtab. 256 blocks (batch) x 256 threads (dim d). LDS double-
// buffered WT-step w tiles; one-step register ping-pong for the broadcast
// ds_reads; packed-f2 math (mv += w*(a - e*mv)). Per tile: 10 uniform qa-
// index loads + 10 coalesced EAtab row gathers, prefetched a tile ahead.
// ---------------------------------------------------------------------------
__global__ __launch_bounds__(256, 1) void scan_kernel(
    const float* __restrict__ Wb, const int* __restrict__ qa_data,
    const u32* __restrict__ EAtab,
    const float* __restrict__ Mv0, float* __restrict__ MvSt,
    u16* __restrict__ RDIE, int CS, int s0, int first)
{
    __shared__ float wt[2][WT * WSTRIDE];   // 2 x 520 floats = 4160 B
    const int b = blockIdx.x;
    const int d = threadIdx.x;

    f2 mv[25];
    if (first) {
#pragma unroll
        for (int j = 0; j < 25; ++j) {
            mv[j].x = Mv0[(2 * j) * DV + d];
            mv[j].y = Mv0[(2 * j + 1) * DV + d];
        }
    } else {
#pragma unroll
        for (int j = 0; j < 25; ++j) {
            mv[j].x = MvSt[((size_t)b * MM + 2 * j) * DV + d];
            mv[j].y = MvSt[((size_t)b * MM + 2 * j + 1) * DV + d];
        }
    }

    const float* wbase = Wb + (size_t)b * CS * WSTRIDE;   // rows contiguous
    const int* qap = qa_data + (size_t)b * SQ + s0;
    u16* rp = RDIE + (size_t)b * CS * 384 + d;

    const int NT = CS / WT;
    const bool loader = (d < (WT * WSTRIDE / 4));   // 130 loader threads

    // Preload tile 0: W -> LDS buf0, ea -> regs (index then gather)
    if (loader) *(float4*)&wt[0][d * 4] = ld4(wbase + d * 4);
    u32 ea[WT];
    {
        int qi[WT];
#pragma unroll
        for (int i = 0; i < WT; ++i) qi[i] = qap[i];
#pragma unroll
        for (int i = 0; i < WT; ++i) ea[i] = EAtab[(size_t)qi[i] * DV + d];
    }
    __syncthreads();

    int cur = 0;
    for (int tile = 0; tile < NT; ++tile) {
        // Prefetch next tile (global -> regs); consumed after this tile
        float4 wreg;
        u32 ean[WT];
        const bool havenext = (tile + 1 < NT);
        if (havenext) {
            if (loader) wreg = ld4(wbase + (size_t)(tile + 1) * WT * WSTRIDE + d * 4);
            int qn[WT];
#pragma unroll
            for (int i = 0; i < WT; ++i) qn[i] = qap[(tile + 1) * WT + i];
#pragma unroll
            for (int i = 0; i < WT; ++i) ean[i] = EAtab[(size_t)qn[i] * DV + d];
        }

        // Register ping-pong over steps; preload step 0
        float4 wpp[2][13];
#pragma unroll
        for (int i = 0; i < 13; ++i)
            wpp[0][i] = *(const float4*)&wt[cur][i * 4];

#pragma unroll
        for (int s = 0; s < WT; ++s) {
            // issue step s+1's broadcast ds_reads into the other bank
            if (s + 1 < WT) {
#pragma unroll
                for (int i = 0; i < 13; ++i)
                    wpp[(s + 1) & 1][i] =
                        *(const float4*)&wt[cur][(s + 1) * WSTRIDE + i * 4];
            }
            const f2* w2 = (const f2*)wpp[s & 1];
            u32 eav = ea[s];
            float e = h2f((u16)(eav & 0xffff));
            float a = h2f((u16)(eav >> 16));
            f2 e2; e2.x = e; e2.y = e;
            f2 a2; a2.x = a; a2.y = a;
            f2 r0 = (f2)0.f, r1 = (f2)0.f, r2 = (f2)0.f, r3 = (f2)0.f;
#pragma unroll
            for (int j = 0; j < 24; j += 4) {
                f2 w_0 = w2[j + 0], w_1 = w2[j + 1], w_2 = w2[j + 2], w_3 = w2[j + 3];
                r0 += w_0 * mv[j + 0];
                r1 += w_1 * mv[j + 1];
                r2 += w_2 * mv[j + 2];
                r3 += w_3 * mv[j + 3];
                f2 t0 = a2 - e2 * mv[j + 0];
                f2 t1 = a2 - e2 * mv[j + 1];
                f2 t2 = a2 - e2 * mv[j + 2];
                f2 t3 = a2 - e2 * mv[j + 3];
                mv[j + 0] += w_0 * t0;
                mv[j + 1] += w_1 * t1;
                mv[j + 2] += w_2 * t2;
                mv[j + 3] += w_3 * t3;
            }
            {
                f2 w24 = w2[24];
                r0 += w24 * mv[24];
                f2 t = a2 - e2 * mv[24];
                mv[24] += w24 * t;
            }
            f2 rs = (r0 + r1) + (r2 + r3);
            rp[(size_t)(tile * WT + s) * 384] = f2h(rs.x + rs.y);
        }

        if (havenext) {
            if (loader) *(float4*)&wt[1 - cur][d * 4] = wreg;
#pragma unroll
            for (int i = 0; i < WT; ++i) ea[i] = ean[i];
            __syncthreads();
            cur ^= 1;
        }
    }

#pragma unroll
    for (int j = 0; j < 25; ++j) {
        MvSt[((size_t)b * MM + 2 * j) * DV + d]     = mv[j].x;
        MvSt[((size_t)b * MM + 2 * j + 1) * DV + d] = mv[j].y;
    }
}

// ---------------------------------------------------------------------------
// loss + outputs
// ---------------------------------------------------------------------------
__global__ __launch_bounds__(256) void loss_part(
    const float* __restrict__ P, const int* __restrict__ target,
    const float* __restrict__ pred_b, float* __restrict__ out,
    float* __restrict__ R2, int s0, int CS, int Nc)
{
    int l = blockIdx.x * 256 + threadIdx.x;
    float le = 0.f, mf = 0.f;
    if (l < Nc) {
        int n = gmap(l, s0, CS);
        float p = P[l] + pred_b[0];
        int t = target[n];
        float y = (t >= 1) ? (float)(t - 1) : 0.f;
        float sig = 1.f / (1.f + __expf(-p));
        if (t >= 1) {
            mf = 1.f;
            le = fmaxf(p, 0.f) + log1pf(__expf(-fabsf(p))) - p * y;
        }
        out[1 + n] = sig * mf;
        out[1 + NROWS + n] = y * mf;
    }
#pragma unroll
    for (int off = 32; off; off >>= 1) {
        le += __shfl_down(le, off);
        mf += __shfl_down(mf, off);
    }
    __shared__ float sl[4], sm[4];
    int wid = threadIdx.x >> 6;
    if ((threadIdx.x & 63) == 0) { sl[wid] = le; sm[wid] = mf; }
    __syncthreads();
    if (threadIdx.x == 0) {
        atomicAdd(R2, sl[0] + sl[1] + sl[2] + sl[3]);
        atomicAdd(R2 + 1, sm[0] + sm[1] + sm[2] + sm[3]);
    }
}

__global__ void loss_fin(const float* __restrict__ R2, float* __restrict__ out)
{
    out[0] = R2[0] / fmaxf(R2[1], 1.f);
}

// ---------------------------------------------------------------------------
extern "C" void kernel_launch(void* const* d_in, const int* in_sizes, int n_in,
                              void* d_out, int out_size, void* d_ws, size_t ws_size,
                              hipStream_t stream)
{
    const int* q_data       = (const int*)d_in[0];
    const int* qa_data      = (const int*)d_in[1];
    const int* target       = (const int*)d_in[2];
    const int* time_data    = (const int*)d_in[3];
    const int* attempt_data = (const int*)d_in[4];
    const int* hint_data    = (const int*)d_in[5];
    const int* hintT_data   = (const int*)d_in[6];
    const float* q_emb    = (const float*)d_in[7];
    const float* qa_emb   = (const float*)d_in[8];
    const float* time_emb = (const float*)d_in[9];
    const float* att_emb  = (const float*)d_in[10];
    const float* ht_emb   = (const float*)d_in[11];
    const float* Mk       = (const float*)d_in[12];
    const float* Mv0      = (const float*)d_in[13];
    const float* diff_W   = (const float*)d_in[14];
    const float* diff_b   = (const float*)d_in[15];
    const float* diff2_W  = (const float*)d_in[16];
    const float* diff2_b  = (const float*)d_in[17];
    const float* erase_W  = (const float*)d_in[18];
    const float* erase_b  = (const float*)d_in[19];
    const float* add_W    = (const float*)d_in[20];
    const float* add_b    = (const float*)d_in[21];
    const float* read_W   = (const float*)d_in[22];
    const float* read_b   = (const float*)d_in[23];
    const float* pred_W   = (const float*)d_in[24];
    const float* pred_b   = (const float*)d_in[25];
    float* out = (float*)d_out;
    (void)in_sizes; (void)n_in; (void)out_size;

    // Adaptive chunking over S (CS must be divisible by WT=10).
    // Per-row bytes: wbuf 208 + bufP 4 + Xp 512 + S3p 256 + QEp 256 + RDIE 768 = 2004
    // Fixed: MvSt 13107200 + R2 16 + weights/qaEh/Mkh 10977792 + EAtab 20578304
    static const int cs_opts[] = {500, 250, 100, 50, 20, 10};
    const size_t FIXED = 44700000ull;
    int CS = 0;
    for (int i = 0; i < 6; ++i) {
        size_t need = (size_t)NB * cs_opts[i] * 2016ull + FIXED;
        if (need <= ws_size) { CS = cs_opts[i]; break; }
    }
    if (CS == 0) return;
    const int NCH = SQ / CS;
    const int Nc = NB * CS;

    // Workspace layout (16B-aligned sections)
    float* MvSt  = (float*)d_ws;                         // [NB*MM*DV]
    float* wbuf  = MvSt + (size_t)NB * MM * DV;          // [Nc*52]
    float* bufP  = wbuf + (size_t)Nc * WSTRIDE;          // [Nc]
    float* bufR2 = bufP + Nc;                            // [4]
    u16*  Xp     = (u16*)(bufR2 + 4);                    // [2Nc*128]
    u16*  S3p    = Xp + (size_t)2 * Nc * 128;            // [Nc*128]
    u16*  QEp    = S3p + (size_t)Nc * 128;               // [Nc*128]
    u16*  RDIE   = QEp + (size_t)Nc * 128;               // [Nc*384]
    u16*  dWh    = RDIE + (size_t)Nc * 384;              // 16384
    u16*  d2Wh   = dWh + 16384;                          // 16384
    u16*  eWh    = d2Wh + 16384;                         // 65536
    u16*  aWh    = eWh + 65536;                          // 65536
    u16*  rWh    = aWh + 65536;                          // 196608
    u16*  qaEh   = rWh + 196608;                         // 5,120,256
    u16*  Mkh    = qaEh + 5120256;                       // 8,192 (64x128)
    u32*  EAtab  = (u32*)(Mkh + 8192);                   // [NQA*256] u32 = 20.6 MB

    // One-time weight/table conversions to fp16
    cvt16<<<16, 256, 0, stream>>>(diff_W,  dWh,  16384 / 4);
    cvt16<<<16, 256, 0, stream>>>(diff2_W, d2Wh, 16384 / 4);
    cvt16<<<64, 256, 0, stream>>>(erase_W, eWh,  65536 / 4);
    cvt16<<<64, 256, 0, stream>>>(add_W,   aWh,  65536 / 4);
    cvt16<<<192, 256, 0, stream>>>(read_W, rWh,  196608 / 4);
    cvt16<<<5001, 256, 0, stream>>>(qa_emb, qaEh, 5120256 / 4);
    mkcvt<<<8, 256, 0, stream>>>(Mk, Mkh);
    hipMemsetAsync(bufR2, 0, 4 * sizeof(float), stream);

    // One-time e/a gate TABLE over all distinct qa indices (NQA rows):
    // replaces the per-row G4 GEMM (6.4x less work; scan gathers by index).
    gemm16<4><<<dim3(NQA / 128, 4), 256, 0, stream>>>(
        qaEh, eWh, aWh, erase_b, add_b, nullptr, nullptr,
        nullptr, nullptr, nullptr, nullptr, (u16*)EAtab, nullptr, 256, 0, 0, 0);

    for (int c = 0; c < NCH; ++c) {
        const int s0 = c * CS;

        prep128<<<Nc / 8, 256, 0, stream>>>(
            q_data, time_data, attempt_data, hint_data, hintT_data,
            q_emb, time_emb, att_emb, ht_emb, Xp, S3p, QEp, s0, CS, Nc);

        // G1: [T1;T2] = tanh(lin1([X1;X2]))  (in-place Xp, 2Nc rows)
        gemm16<1><<<dim3(2 * Nc / 128, 1), 256, 0, stream>>>(
            Xp, dWh, nullptr, diff_b, nullptr, Xp, nullptr,
            nullptr, nullptr, nullptr, nullptr, nullptr, nullptr, 128, Nc, s0, CS);
        // G2: sig(lin2): rows<Nc -> tf; rows>=Nc -> x3 = qe + df*s3  (in-place)
        gemm16<2><<<dim3(2 * Nc / 128, 1), 256, 0, stream>>>(
            Xp, d2Wh, nullptr, diff2_b, nullptr, Xp, nullptr,
            QEp, S3p, nullptr, nullptr, nullptr, nullptr, 128, Nc, s0, CS);
        // G3: qp = lin1(x3) -> Xp[0:Nc); fused ie = qp + tf*te -> RDIE[:,256:)
        gemm16<3><<<dim3(Nc / 128, 1), 256, 0, stream>>>(
            Xp + (size_t)Nc * 128, dWh, nullptr, diff_b, nullptr, Xp, nullptr,
            nullptr, nullptr, time_data, time_emb, RDIE, nullptr, 128, Nc, s0, CS);
        // w = softmax(qp @ Mk^T) via MFMA
        wsoftmax_mfma<<<Nc / 128, 256, 0, stream>>>(Xp, Mkh, wbuf);
        // scan -> RD fp16 into RDIE[:,0:256); e/a gathered from EAtab
        scan_kernel<<<NB, DV, 0, stream>>>(
            wbuf, qa_data, EAtab, Mv0, MvSt, RDIE, CS, s0, c == 0 ? 1 : 0);

        hipMemsetAsync(bufP, 0, (size_t)Nc * sizeof(float), stream);
        // G5: rc = tanh([rd|ie] @ read_W^T + b); pred partials -> bufP
        gemm16<5><<<dim3(Nc / 128, 4), 256, 0, stream>>>(
            RDIE, rWh, nullptr, read_b, nullptr, nullptr, bufP,
            nullptr, nullptr, nullptr, nullptr, nullptr, pred_W, 384, Nc, s0, CS);

        loss_part<<<Nc / 256, 256, 0, stream>>>(bufP, target, pred_b, out, bufR2, s0, CS, Nc);
    }

    loss_fin<<<1, 1, 0, stream>>>(bufR2, out);
}

// Round 8
// 686.594 us; speedup vs baseline: 1.7493x; 1.0522x over previous
//
#include <hip/hip_runtime.h>
#include <cstdint>
#include <cstddef>

// Problem constants
#define NB 256
#define SQ 500
#define NROWS (NB * SQ)   // 128000
#define DQ 128
#define DV 256
#define MM 50
#define FF 512
#define NQA 20096         // padded distinct qa indices (2*NQ+1 = 20001 -> 157*128)
#define WSTRIDE 52        // padded w-row stride (16B aligned)
#define WT 10             // scan LDS tile: steps per stage

typedef _Float16 half8 __attribute__((ext_vector_type(8)));
typedef float floatx4 __attribute__((ext_vector_type(4)));
typedef float f2 __attribute__((ext_vector_type(2)));
typedef unsigned int u32;
typedef unsigned short u16;

typedef __attribute__((address_space(1))) void gvoid;
typedef __attribute__((address_space(3))) void lvoid;

// async global->LDS, 16B per lane; LDS dest is wave-uniform base + lane*16
__device__ __forceinline__ void gl16(const u16* g, u16* l) {
    __builtin_amdgcn_global_load_lds((gvoid*)g, (lvoid*)l, 16, 0, 0);
}

__device__ __forceinline__ float4 ld4(const float* p) {
    return *reinterpret_cast<const float4*>(p);
}
__device__ __forceinline__ float sigf(float x) { return 1.f / (1.f + __expf(-x)); }
__device__ __forceinline__ float tanhfast(float x) { return 2.f / (1.f + __expf(-2.f * x)) - 1.f; }
__device__ __forceinline__ int gmap(int l, int s0, int CS) {
    int b = (unsigned)l / (unsigned)CS;
    return b * SQ + s0 + (l - b * CS);
}
__device__ __forceinline__ void st4h(u16* dst, float4 v) {
    _Float16 h0 = (_Float16)v.x, h1 = (_Float16)v.y, h2 = (_Float16)v.z, h3 = (_Float16)v.w;
    ushort4 u;
    u.x = *(u16*)&h0; u.y = *(u16*)&h1; u.z = *(u16*)&h2; u.w = *(u16*)&h3;
    *(ushort4*)dst = u;
}
__device__ __forceinline__ float h2f(u16 b) { _Float16 h; *(u16*)&h = b; return (float)h; }
__device__ __forceinline__ u16 f2h(float x) { _Float16 h = (_Float16)x; return *(u16*)&h; }

// ---------------------------------------------------------------------------
// fp32 -> fp16 conversion (vec4)
// ---------------------------------------------------------------------------
__global__ __launch_bounds__(256) void cvt16(
    const float* __restrict__ s, u16* __restrict__ d, int n4)
{
    int i = blockIdx.x * 256 + threadIdx.x;
    if (i < n4) st4h(d + 4 * (size_t)i, ld4(s + 4 * (size_t)i));
}

// ---------------------------------------------------------------------------
// Mk [50,128] fp32 -> Mkh [64,128] fp16, rows 50..63 zeroed
// ---------------------------------------------------------------------------
__global__ __launch_bounds__(256) void mkcvt(
    const float* __restrict__ Mk, u16* __restrict__ Mkh)
{
    int i = blockIdx.x * 256 + threadIdx.x;   // 2048 float4 slots
    if (i >= 64 * 32) return;
    int row = i >> 5;
    float4 v = (row < MM) ? ld4(Mk + (size_t)row * DQ + (i & 31) * 4)
                          : float4{0.f, 0.f, 0.f, 0.f};
    st4h(Mkh + 4 * (size_t)i, v);
}

// ---------------------------------------------------------------------------
// prep: Xp rows [0,Nc) = fp16(te+qe); rows [Nc,2Nc) = fp16(he+hte+ae+qe);
//       S3p = fp16(he+hte+ae); QEp = fp16(qe)
// ---------------------------------------------------------------------------
__global__ __launch_bounds__(256) void prep128(
    const int* __restrict__ q_data, const int* __restrict__ time_data,
    const int* __restrict__ attempt_data, const int* __restrict__ hint_data,
    const int* __restrict__ hintT_data,
    const float* __restrict__ q_emb, const float* __restrict__ time_emb,
    const float* __restrict__ attempt_emb, const float* __restrict__ ht_emb,
    u16* __restrict__ Xp, u16* __restrict__ S3p, u16* __restrict__ QEp,
    int s0, int CS, int Nc)
{
    int g = blockIdx.x * 256 + threadIdx.x;
    int l = g >> 5;
    int kq = (g & 31) << 2;
    if (l >= Nc) return;
    int n = gmap(l, s0, CS);
    float4 qe  = ld4(q_emb       + (size_t)q_data[n]       * DQ + kq);
    float4 te  = ld4(time_emb    + (size_t)time_data[n]    * DQ + kq);
    float4 ae  = ld4(attempt_emb + (size_t)attempt_data[n] * DQ + kq);
    float4 he  = ld4(ht_emb      + (size_t)hint_data[n]    * DQ + kq);
    float4 hte = ld4(ht_emb      + (size_t)hintT_data[n]   * DQ + kq);
    size_t off = (size_t)l * DQ + kq;
    float4 x1, s3, x2;
    x1.x = te.x + qe.x; x1.y = te.y + qe.y; x1.z = te.z + qe.z; x1.w = te.w + qe.w;
    s3.x = he.x + hte.x + ae.x; s3.y = he.y + hte.y + ae.y;
    s3.z = he.z + hte.z + ae.z; s3.w = he.w + hte.w + ae.w;
    x2.x = s3.x + qe.x; x2.y = s3.y + qe.y; x2.z = s3.z + qe.z; x2.w = s3.w + qe.w;
    st4h(Xp + off, x1);
    st4h(Xp + (size_t)Nc * DQ + off, x2);
    st4h(S3p + off, s3);
    st4h(QEp + off, qe);
}

// ---------------------------------------------------------------------------
// fp16 MFMA GEMM: Y = epi(act(A @ W^T + bias)), BM=BN=128, BK=64, 4 waves,
// wave tile 64x64 = 4x4 of v_mfma_f32_16x16x32_f16.
// m97 structure: global_load_lds width-16 staging into linear [128][64]
// fp16 LDS tiles with XOR-granule swizzle (lg = g ^ (row&7)) applied on the
// GLOBAL source at stage time and on the LDS offset at read time — 16-lane
// fragment reads spread over 8 banks (2-way = free, m136).
// MODE 1: tanh -> fp16 Yh (stride 128)               [lin1 on 2Nc rows]
// MODE 2: sig; row<Nc: tf->Yh; row>=Nc: x3=qe+v*s3 -> Yh  [lin2 batched]
// MODE 3: none; qp->Yh; fused ie=qp+tf*te -> AUX[,256:384] [lin1(X3)+ew_ie]
// MODE 4: e/a TABLE build over qa indices; by<2: sig->e else tanh->a -> AUX
// MODE 5: tanh(rc); pred-partial reduce -> atomicAdd Yf    [readout+pred]
// ---------------------------------------------------------------------------
template <int MODE>
__global__ __launch_bounds__(256, 2) void gemm16(
    const u16* __restrict__ A, const u16* __restrict__ W0,
    const u16* __restrict__ W1, const float* __restrict__ b0,
    const float* __restrict__ b1, u16* __restrict__ Yh,
    float* __restrict__ Yf,
    const u16* __restrict__ QEp, const u16* __restrict__ S3p,
    const int* __restrict__ idx, const float* __restrict__ gtab,
    u16* __restrict__ AUX, const float* __restrict__ predW,
    int K, int Nc, int s0, int CS)
{
    __shared__ u16 smem[2 * 128 * 64];   // 32768 B: At | Bt, BK=64 linear+swz
    u16* At = smem;
    u16* Bt = smem + 128 * 64;
    const int tid = threadIdx.x;
    const int row0 = blockIdx.x * 128;
    const int by = blockIdx.y;

    const u16* Wp;
    int col0;
    if constexpr (MODE == 4) { Wp = (by < 2) ? W0 : W1; col0 = (by & 1) * 128; }
    else { Wp = W0; col0 = by * 128; }
    const float* bias = (MODE == 4 && by >= 2) ? b1 : b0;

    floatx4 acc[4][4];
#pragma unroll
    for (int m = 0; m < 4; ++m)
#pragma unroll
        for (int n = 0; n < 4; ++n) acc[m][n] = (floatx4)0.f;

    const int lane = tid & 63, wv = tid >> 6;
    const int wr = (wv >> 1) * 64, wc = (wv & 1) * 64;
    const int q = lane >> 4, c0 = lane & 15;

    for (int kt = 0; kt < K; kt += 64) {
        // stage A-tile: 1024 granules of 16B, lane-linear LDS dest,
        // source granule XOR-swizzled: physical[r][g] = logical[r][g^(r&7)]
#pragma unroll
        for (int j = 0; j < 4; ++j) {
            int f = tid + j * 256;          // [0,1024)
            int r = f >> 3;
            int lg = (f & 7) ^ (r & 7);
            gl16(A + (size_t)(row0 + r) * K + kt + lg * 8, &At[f * 8]);
        }
#pragma unroll
        for (int j = 0; j < 4; ++j) {
            int f = tid + j * 256;
            int r = f >> 3;
            int lg = (f & 7) ^ (r & 7);
            gl16(Wp + (size_t)(col0 + r) * K + kt + lg * 8, &Bt[f * 8]);
        }
        __syncthreads();
#pragma unroll
        for (int kk = 0; kk < 2; ++kk) {
            half8 af[4], bf[4];
#pragma unroll
            for (int m = 0; m < 4; ++m) {
                int row = wr + m * 16 + c0;
                af[m] = *(half8*)&At[row * 64 + ((((kk << 2) | q)) ^ (row & 7)) * 8];
            }
#pragma unroll
            for (int n = 0; n < 4; ++n) {
                int row = wc + n * 16 + c0;
                bf[n] = *(half8*)&Bt[row * 64 + ((((kk << 2) | q)) ^ (row & 7)) * 8];
            }
#pragma unroll
            for (int m = 0; m < 4; ++m)
#pragma unroll
                for (int n = 0; n < 4; ++n)
                    acc[m][n] = __builtin_amdgcn_mfma_f32_16x16x32_f16(af[m], bf[n], acc[m][n], 0, 0, 0);
        }
        __syncthreads();
    }

    float bv[4];
#pragma unroll
    for (int n = 0; n < 4; ++n) bv[n] = bias[col0 + wc + n * 16 + c0];

    if constexpr (MODE == 5) {
        float pw[4];
#pragma unroll
        for (int n = 0; n < 4; ++n) pw[n] = predW[col0 + wc + n * 16 + c0];
        float* red = (float*)smem;          // [128][33] = 16896 B <= 32768
#pragma unroll
        for (int m = 0; m < 4; ++m)
#pragma unroll
            for (int r4 = 0; r4 < 4; ++r4) {
                int row = wr + m * 16 + q * 4 + r4;
                float pp = 0.f;
#pragma unroll
                for (int n = 0; n < 4; ++n)
                    pp = fmaf(tanhfast(acc[m][n][r4] + bv[n]), pw[n], pp);
                red[row * 33 + (wv & 1) * 16 + c0] = pp;
            }
        __syncthreads();
        if (tid < 128) {
            float s = 0.f;
#pragma unroll
            for (int j = 0; j < 32; ++j) s += red[tid * 33 + j];
            atomicAdd(&Yf[row0 + tid], s);
        }
    } else {
#pragma unroll
        for (int m = 0; m < 4; ++m)
#pragma unroll
            for (int r4 = 0; r4 < 4; ++r4) {
                int row = row0 + wr + m * 16 + q * 4 + r4;
#pragma unroll
                for (int n = 0; n < 4; ++n) {
                    int col = col0 + wc + n * 16 + c0;
                    float v = acc[m][n][r4] + bv[n];
                    if constexpr (MODE == 1) {
                        Yh[(size_t)row * 128 + col] = f2h(tanhfast(v));
                    } else if constexpr (MODE == 2) {
                        v = sigf(v);
                        if (row < Nc) {
                            Yh[(size_t)row * 128 + col] = f2h(v);
                        } else {
                            size_t o = (size_t)(row - Nc) * 128 + col;
                            float qe = h2f(QEp[o]), s3 = h2f(S3p[o]);
                            Yh[(size_t)row * 128 + col] = f2h(fmaf(v, s3, qe));
                        }
                    } else if constexpr (MODE == 3) {
                        size_t o = (size_t)row * 128 + col;
                        float tf = h2f(Yh[o]);   // read tf BEFORE overwriting with qp
                        float te = gtab[(size_t)idx[gmap(row, s0, CS)] * 128 + col];
                        AUX[(size_t)row * 384 + 256 + col] = f2h(fmaf(tf, te, v));
                        Yh[o] = f2h(v);
                    } else { // MODE 4
                        bool isE = (by < 2);
                        v = isE ? sigf(v) : tanhfast(v);
                        AUX[((size_t)row * 256 + col) * 2 + (isE ? 0 : 1)] = f2h(v);
                    }
                }
            }
    }
}

// ---------------------------------------------------------------------------
// w = softmax(qp @ Mk^T) via MFMA. Block: 128 rows x 64 cols (50 live).
// Logits -> LDS (pitch 67: conflict-free column reads), row softmax,
// coalesced float4 store to Wb (stride WSTRIDE).
// ---------------------------------------------------------------------------
__global__ __launch_bounds__(256) void wsoftmax_mfma(
    const u16* __restrict__ QP, const u16* __restrict__ Mkh,
    float* __restrict__ Wb)
{
    __shared__ float Sred[128 * 67];        // 34304 B; head doubles as At/Bt
    u16* At = (u16*)Sred;                   // [128][40] fp16 = 10240 B
    u16* Bt = At + 128 * 40;                // [64][40]  fp16 =  5120 B
    const int tid = threadIdx.x;
    const int row0 = blockIdx.x * 128;
    const int lane = tid & 63, wv = tid >> 6;
    const int wr = wv * 32;                 // wave: 32 rows x 64 cols
    const int q = lane >> 4, c0 = lane & 15;

    floatx4 acc[2][4];
#pragma unroll
    for (int m = 0; m < 2; ++m)
#pragma unroll
        for (int n = 0; n < 4; ++n) acc[m][n] = (floatx4)0.f;

    for (int kt = 0; kt < DQ; kt += 32) {
#pragma unroll
        for (int i = 0; i < 3; ++i) {
            int c = tid + i * 256;          // [0,768)
            if (c < 512) {
                int r = c >> 2, seg = c & 3;
                *(uint4*)&At[r * 40 + seg * 8] =
                    *(const uint4*)(QP + (size_t)(row0 + r) * DQ + kt + seg * 8);
            } else {
                int cb = c - 512;
                int r = cb >> 2, seg = cb & 3;
                *(uint4*)&Bt[r * 40 + seg * 8] =
                    *(const uint4*)(Mkh + (size_t)r * DQ + kt + seg * 8);
            }
        }
        __syncthreads();
        half8 af[2], bf[4];
#pragma unroll
        for (int m = 0; m < 2; ++m) af[m] = *(half8*)&At[(wr + m * 16 + c0) * 40 + q * 8];
#pragma unroll
        for (int n = 0; n < 4; ++n) bf[n] = *(half8*)&Bt[(n * 16 + c0) * 40 + q * 8];
#pragma unroll
        for (int m = 0; m < 2; ++m)
#pragma unroll
            for (int n = 0; n < 4; ++n)
                acc[m][n] = __builtin_amdgcn_mfma_f32_16x16x32_f16(af[m], bf[n], acc[m][n], 0, 0, 0);
        __syncthreads();
    }

    // dump logits to LDS: row = wr + m*16 + q*4 + r, col = n*16 + c0
#pragma unroll
    for (int m = 0; m < 2; ++m)
#pragma unroll
        for (int r4 = 0; r4 < 4; ++r4) {
            int row = wr + m * 16 + q * 4 + r4;
#pragma unroll
            for (int n = 0; n < 4; ++n)
                Sred[row * 67 + n * 16 + c0] = acc[m][n][r4];
        }
    __syncthreads();

    // row-wise softmax over 50 live cols (one thread per row)
    if (tid < 128) {
        float* s = &Sred[tid * 67];
        float mx = -3.0e38f;
#pragma unroll
        for (int m = 0; m < MM; ++m) mx = fmaxf(mx, s[m]);
        float sum = 0.f;
#pragma unroll
        for (int m = 0; m < MM; ++m) { float e = __expf(s[m] - mx); s[m] = e; sum += e; }
        float inv = 1.f / sum;
#pragma unroll
        for (int m = 0; m < MM; ++m) s[m] *= inv;
        s[50] = 0.f; s[51] = 0.f;
    }
    __syncthreads();

    // coalesced store: 128 rows x 13 float4
    for (int i = tid; i < 128 * 13; i += 256) {
        int row = i / 13, seg = i - row * 13;
        float4 v;
        v.x = Sred[row * 67 + seg * 4 + 0];
        v.y = Sred[row * 67 + seg * 4 + 1];
        v.z = Sred[row * 67 + seg * 4 + 2];
        v.w = Sred[row * 67 + seg * 4 + 3];
        *(float4*)(Wb + (size_t)(row0 + row) * WSTRIDE + seg * 4) = v;
    }
}

// ---------------------------------------------------------------------------
// DKVMN scan v9 (best measured: 98.5us): 256 blocks (batch) x 256 threads
// (dim d). LDS double-buffered WT-step w tiles; one-step register ping-pong
// for the broadcast ds_reads; packed-f2 math (mv += w*(a - e*mv)). e/a
// gathered from the per-qa-index table EAtab, prefetched a tile ahead.
// ---------------------------------------------------------------------------
__global__ __launch_bounds__(256, 1) void scan_kernel(
    const float* __restrict__ Wb, const int* __restrict__ qa_data,
    const u32* __restrict__ EAtab,
    const float* __restrict__ Mv0, float* __restrict__ MvSt,
    u16* __restrict__ RDIE, int CS, int s0, int first)
{
    __shared__ float wt[2][WT * WSTRIDE];   // 2 x 520 floats = 4160 B
    const int b = blockIdx.x;
    const int d = threadIdx.x;

    f2 mv[25];
    if (first) {
#pragma unroll
        for (int j = 0; j < 25; ++j) {
            mv[j].x = Mv0[(2 * j) * DV + d];
            mv[j].y = Mv0[(2 * j + 1) * DV + d];
        }
    } else {
#pragma unroll
        for (int j = 0; j < 25; ++j) {
            mv[j].x = MvSt[((size_t)b * MM + 2 * j) * DV + d];
            mv[j].y = MvSt[((size_t)b * MM + 2 * j + 1) * DV + d];
        }
    }

    const float* wbase = Wb + (size_t)b * CS * WSTRIDE;   // rows contiguous
    const int* qap = qa_data + (size_t)b * SQ + s0;
    u16* rp = RDIE + (size_t)b * CS * 384 + d;

    const int NT = CS / WT;
    const bool loader = (d < (WT * WSTRIDE / 4));   // 130 loader threads

    // Preload tile 0: W -> LDS buf0, ea -> regs (index then gather)
    if (loader) *(float4*)&wt[0][d * 4] = ld4(wbase + d * 4);
    u32 ea[WT];
    {
        int qi[WT];
#pragma unroll
        for (int i = 0; i < WT; ++i) qi[i] = qap[i];
#pragma unroll
        for (int i = 0; i < WT; ++i) ea[i] = EAtab[(size_t)qi[i] * DV + d];
    }
    __syncthreads();

    int cur = 0;
    for (int tile = 0; tile < NT; ++tile) {
        // Prefetch next tile (global -> regs); consumed after this tile
        float4 wreg;
        u32 ean[WT];
        const bool havenext = (tile + 1 < NT);
        if (havenext) {
            if (loader) wreg = ld4(wbase + (size_t)(tile + 1) * WT * WSTRIDE + d * 4);
            int qn[WT];
#pragma unroll
            for (int i = 0; i < WT; ++i) qn[i] = qap[(tile + 1) * WT + i];
#pragma unroll
            for (int i = 0; i < WT; ++i) ean[i] = EAtab[(size_t)qn[i] * DV + d];
        }

        // Register ping-pong over steps; preload step 0
        float4 wpp[2][13];
#pragma unroll
        for (int i = 0; i < 13; ++i)
            wpp[0][i] = *(const float4*)&wt[cur][i * 4];

#pragma unroll
        for (int s = 0; s < WT; ++s) {
            // issue step s+1's broadcast ds_reads into the other bank
            if (s + 1 < WT) {
#pragma unroll
                for (int i = 0; i < 13; ++i)
                    wpp[(s + 1) & 1][i] =
                        *(const float4*)&wt[cur][(s + 1) * WSTRIDE + i * 4];
            }
            const f2* w2 = (const f2*)wpp[s & 1];
            u32 eav = ea[s];
            float e = h2f((u16)(eav & 0xffff));
            float a = h2f((u16)(eav >> 16));
            f2 e2; e2.x = e; e2.y = e;
            f2 a2; a2.x = a; a2.y = a;
            f2 r0 = (f2)0.f, r1 = (f2)0.f, r2 = (f2)0.f, r3 = (f2)0.f;
#pragma unroll
            for (int j = 0; j < 24; j += 4) {
                f2 w_0 = w2[j + 0], w_1 = w2[j + 1], w_2 = w2[j + 2], w_3 = w2[j + 3];
                r0 += w_0 * mv[j + 0];
                r1 += w_1 * mv[j + 1];
                r2 += w_2 * mv[j + 2];
                r3 += w_3 * mv[j + 3];
                f2 t0 = a2 - e2 * mv[j + 0];
                f2 t1 = a2 - e2 * mv[j + 1];
                f2 t2 = a2 - e2 * mv[j + 2];
                f2 t3 = a2 - e2 * mv[j + 3];
                mv[j + 0] += w_0 * t0;
                mv[j + 1] += w_1 * t1;
                mv[j + 2] += w_2 * t2;
                mv[j + 3] += w_3 * t3;
            }
            {
                f2 w24 = w2[24];
                r0 += w24 * mv[24];
                f2 t = a2 - e2 * mv[24];
                mv[24] += w24 * t;
            }
            f2 rs = (r0 + r1) + (r2 + r3);
            rp[(size_t)(tile * WT + s) * 384] = f2h(rs.x + rs.y);
        }

        if (havenext) {
            if (loader) *(float4*)&wt[1 - cur][d * 4] = wreg;
#pragma unroll
            for (int i = 0; i < WT; ++i) ea[i] = ean[i];
            __syncthreads();
            cur ^= 1;
        }
    }

#pragma unroll
    for (int j = 0; j < 25; ++j) {
        MvSt[((size_t)b * MM + 2 * j) * DV + d]     = mv[j].x;
        MvSt[((size_t)b * MM + 2 * j + 1) * DV + d] = mv[j].y;
    }
}

// ---------------------------------------------------------------------------
// loss + outputs
// ---------------------------------------------------------------------------
__global__ __launch_bounds__(256) void loss_part(
    const float* __restrict__ P, const int* __restrict__ target,
    const float* __restrict__ pred_b, float* __restrict__ out,
    float* __restrict__ R2, int s0, int CS, int Nc)
{
    int l = blockIdx.x * 256 + threadIdx.x;
    float le = 0.f, mf = 0.f;
    if (l < Nc) {
        int n = gmap(l, s0, CS);
        float p = P[l] + pred_b[0];
        int t = target[n];
        float y = (t >= 1) ? (float)(t - 1) : 0.f;
        float sig = 1.f / (1.f + __expf(-p));
        if (t >= 1) {
            mf = 1.f;
            le = fmaxf(p, 0.f) + log1pf(__expf(-fabsf(p))) - p * y;
        }
        out[1 + n] = sig * mf;
        out[1 + NROWS + n] = y * mf;
    }
#pragma unroll
    for (int off = 32; off; off >>= 1) {
        le += __shfl_down(le, off);
        mf += __shfl_down(mf, off);
    }
    __shared__ float sl[4], sm[4];
    int wid = threadIdx.x >> 6;
    if ((threadIdx.x & 63) == 0) { sl[wid] = le; sm[wid] = mf; }
    __syncthreads();
    if (threadIdx.x == 0) {
        atomicAdd(R2, sl[0] + sl[1] + sl[2] + sl[3]);
        atomicAdd(R2 + 1, sm[0] + sm[1] + sm[2] + sm[3]);
    }
}

__global__ void loss_fin(const float* __restrict__ R2, float* __restrict__ out)
{
    out[0] = R2[0] / fmaxf(R2[1], 1.f);
}

// ---------------------------------------------------------------------------
extern "C" void kernel_launch(void* const* d_in, const int* in_sizes, int n_in,
                              void* d_out, int out_size, void* d_ws, size_t ws_size,
                              hipStream_t stream)
{
    const int* q_data       = (const int*)d_in[0];
    const int* qa_data      = (const int*)d_in[1];
    const int* target       = (const int*)d_in[2];
    const int* time_data    = (const int*)d_in[3];
    const int* attempt_data = (const int*)d_in[4];
    const int* hint_data    = (const int*)d_in[5];
    const int* hintT_data   = (const int*)d_in[6];
    const float* q_emb    = (const float*)d_in[7];
    const float* qa_emb   = (const float*)d_in[8];
    const float* time_emb = (const float*)d_in[9];
    const float* att_emb  = (const float*)d_in[10];
    const float* ht_emb   = (const float*)d_in[11];
    const float* Mk       = (const float*)d_in[12];
    const float* Mv0      = (const float*)d_in[13];
    const float* diff_W   = (const float*)d_in[14];
    const float* diff_b   = (const float*)d_in[15];
    const float* diff2_W  = (const float*)d_in[16];
    const float* diff2_b  = (const float*)d_in[17];
    const float* erase_W  = (const float*)d_in[18];
    const float* erase_b  = (const float*)d_in[19];
    const float* add_W    = (const float*)d_in[20];
    const float* add_b    = (const float*)d_in[21];
    const float* read_W   = (const float*)d_in[22];
    const float* read_b   = (const float*)d_in[23];
    const float* pred_W   = (const float*)d_in[24];
    const float* pred_b   = (const float*)d_in[25];
    float* out = (float*)d_out;
    (void)in_sizes; (void)n_in; (void)out_size;

    // Adaptive chunking over S (CS must be divisible by WT=10).
    static const int cs_opts[] = {500, 250, 100, 50, 20, 10};
    const size_t FIXED = 44700000ull;
    int CS = 0;
    for (int i = 0; i < 6; ++i) {
        size_t need = (size_t)NB * cs_opts[i] * 2016ull + FIXED;
        if (need <= ws_size) { CS = cs_opts[i]; break; }
    }
    if (CS == 0) return;
    const int NCH = SQ / CS;
    const int Nc = NB * CS;

    // Workspace layout (16B-aligned sections)
    float* MvSt  = (float*)d_ws;                         // [NB*MM*DV]
    float* wbuf  = MvSt + (size_t)NB * MM * DV;          // [Nc*52]
    float* bufP  = wbuf + (size_t)Nc * WSTRIDE;          // [Nc]
    float* bufR2 = bufP + Nc;                            // [4]
    u16*  Xp     = (u16*)(bufR2 + 4);                    // [2Nc*128]
    u16*  S3p    = Xp + (size_t)2 * Nc * 128;            // [Nc*128]
    u16*  QEp    = S3p + (size_t)Nc * 128;               // [Nc*128]
    u16*  RDIE   = QEp + (size_t)Nc * 128;               // [Nc*384]
    u16*  dWh    = RDIE + (size_t)Nc * 384;              // 16384
    u16*  d2Wh   = dWh + 16384;                          // 16384
    u16*  eWh    = d2Wh + 16384;                         // 65536
    u16*  aWh    = eWh + 65536;                          // 65536
    u16*  rWh    = aWh + 65536;                          // 196608
    u16*  qaEh   = rWh + 196608;                         // 5,120,256
    u16*  Mkh    = qaEh + 5120256;                       // 8,192 (64x128)
    u32*  EAtab  = (u32*)(Mkh + 8192);                   // [NQA*256] u32 = 20.6 MB

    // One-time weight/table conversions to fp16
    cvt16<<<16, 256, 0, stream>>>(diff_W,  dWh,  16384 / 4);
    cvt16<<<16, 256, 0, stream>>>(diff2_W, d2Wh, 16384 / 4);
    cvt16<<<64, 256, 0, stream>>>(erase_W, eWh,  65536 / 4);
    cvt16<<<64, 256, 0, stream>>>(add_W,   aWh,  65536 / 4);
    cvt16<<<192, 256, 0, stream>>>(read_W, rWh,  196608 / 4);
    cvt16<<<5001, 256, 0, stream>>>(qa_emb, qaEh, 5120256 / 4);
    mkcvt<<<8, 256, 0, stream>>>(Mk, Mkh);
    hipMemsetAsync(bufR2, 0, 4 * sizeof(float), stream);

    // One-time e/a gate TABLE over all distinct qa indices (NQA rows)
    gemm16<4><<<dim3(NQA / 128, 4), 256, 0, stream>>>(
        qaEh, eWh, aWh, erase_b, add_b, nullptr, nullptr,
        nullptr, nullptr, nullptr, nullptr, (u16*)EAtab, nullptr, 256, 0, 0, 0);

    for (int c = 0; c < NCH; ++c) {
        const int s0 = c * CS;

        prep128<<<Nc / 8, 256, 0, stream>>>(
            q_data, time_data, attempt_data, hint_data, hintT_data,
            q_emb, time_emb, att_emb, ht_emb, Xp, S3p, QEp, s0, CS, Nc);

        // G1: [T1;T2] = tanh(lin1([X1;X2]))  (in-place Xp, 2Nc rows)
        gemm16<1><<<dim3(2 * Nc / 128, 1), 256, 0, stream>>>(
            Xp, dWh, nullptr, diff_b, nullptr, Xp, nullptr,
            nullptr, nullptr, nullptr, nullptr, nullptr, nullptr, 128, Nc, s0, CS);
        // G2: sig(lin2): rows<Nc -> tf; rows>=Nc -> x3 = qe + df*s3  (in-place)
        gemm16<2><<<dim3(2 * Nc / 128, 1), 256, 0, stream>>>(
            Xp, d2Wh, nullptr, diff2_b, nullptr, Xp, nullptr,
            QEp, S3p, nullptr, nullptr, nullptr, nullptr, 128, Nc, s0, CS);
        // G3: qp = lin1(x3) -> Xp[0:Nc); fused ie = qp + tf*te -> RDIE[:,256:)
        gemm16<3><<<dim3(Nc / 128, 1), 256, 0, stream>>>(
            Xp + (size_t)Nc * 128, dWh, nullptr, diff_b, nullptr, Xp, nullptr,
            nullptr, nullptr, time_data, time_emb, RDIE, nullptr, 128, Nc, s0, CS);
        // w = softmax(qp @ Mk^T) via MFMA
        wsoftmax_mfma<<<Nc / 128, 256, 0, stream>>>(Xp, Mkh, wbuf);
        // scan -> RD fp16 into RDIE[:,0:256); e/a gathered from EAtab
        scan_kernel<<<NB, DV, 0, stream>>>(
            wbuf, qa_data, EAtab, Mv0, MvSt, RDIE, CS, s0, c == 0 ? 1 : 0);

        hipMemsetAsync(bufP, 0, (size_t)Nc * sizeof(float), stream);
        // G5: rc = tanh([rd|ie] @ read_W^T + b); pred partials -> bufP
        gemm16<5><<<dim3(Nc / 128, 4), 256, 0, stream>>>(
            RDIE, rWh, nullptr, read_b, nullptr, nullptr, bufP,
            nullptr, nullptr, nullptr, nullptr, nullptr, pred_W, 384, Nc, s0, CS);

        loss_part<<<Nc / 256, 256, 0, stream>>>(bufP, target, pred_b, out, bufR2, s0, CS, Nc);
    }

    loss_fin<<<1, 1, 0, stream>>>(bufR2, out);
}

// Round 9
// 645.635 us; speedup vs baseline: 1.8603x; 1.0634x over previous
//
#include <hip/hip_runtime.h>
#include <cstdint>
#include <cstddef>

// Problem constants
#define NB 256
#define SQ 500
#define NROWS (NB * SQ)   // 128000
#define DQ 128
#define DV 256
#define MM 50
#define FF 512
#define NQA 20096         // padded distinct qa indices (2*NQ+1 = 20001 -> 157*128)
#define WSTRIDE 52        // padded w-row stride (16B aligned)
#define WT 10             // scan LDS tile: steps per stage

typedef _Float16 half8 __attribute__((ext_vector_type(8)));
typedef float floatx4 __attribute__((ext_vector_type(4)));
typedef float f2 __attribute__((ext_vector_type(2)));
typedef unsigned int u32;
typedef unsigned short u16;

typedef __attribute__((address_space(1))) void gvoid;
typedef __attribute__((address_space(3))) void lvoid;

// async global->LDS, 16B per lane; LDS dest is wave-uniform base + lane*16
__device__ __forceinline__ void gl16(const u16* g, u16* l) {
    __builtin_amdgcn_global_load_lds((gvoid*)g, (lvoid*)l, 16, 0, 0);
}

__device__ __forceinline__ float4 ld4(const float* p) {
    return *reinterpret_cast<const float4*>(p);
}
__device__ __forceinline__ float sigf(float x) { return 1.f / (1.f + __expf(-x)); }
__device__ __forceinline__ float tanhfast(float x) { return 2.f / (1.f + __expf(-2.f * x)) - 1.f; }
__device__ __forceinline__ int gmap(int l, int s0, int CS) {
    int b = (unsigned)l / (unsigned)CS;
    return b * SQ + s0 + (l - b * CS);
}
__device__ __forceinline__ void st4h(u16* dst, float4 v) {
    _Float16 h0 = (_Float16)v.x, h1 = (_Float16)v.y, h2 = (_Float16)v.z, h3 = (_Float16)v.w;
    ushort4 u;
    u.x = *(u16*)&h0; u.y = *(u16*)&h1; u.z = *(u16*)&h2; u.w = *(u16*)&h3;
    *(ushort4*)dst = u;
}
__device__ __forceinline__ float h2f(u16 b) { _Float16 h; *(u16*)&h = b; return (float)h; }
__device__ __forceinline__ u16 f2h(float x) { _Float16 h = (_Float16)x; return *(u16*)&h; }

// ---------------------------------------------------------------------------
// fp32 -> fp16 conversion (vec4)
// ---------------------------------------------------------------------------
__global__ __launch_bounds__(256) void cvt16(
    const float* __restrict__ s, u16* __restrict__ d, int n4)
{
    int i = blockIdx.x * 256 + threadIdx.x;
    if (i < n4) st4h(d + 4 * (size_t)i, ld4(s + 4 * (size_t)i));
}

// ---------------------------------------------------------------------------
// fused fp16 conversion of the 5 weight matrices (contiguous dst layout):
// [0,4096): diff_W  [4096,8192): diff2_W  [8192,24576): erase_W
// [24576,40960): add_W  [40960,90112): read_W      (units: float4 groups)
// ---------------------------------------------------------------------------
__global__ __launch_bounds__(256) void wcvt(
    const float* __restrict__ s0, const float* __restrict__ s1,
    const float* __restrict__ s2, const float* __restrict__ s3,
    const float* __restrict__ s4, u16* __restrict__ dst)
{
    int i = blockIdx.x * 256 + threadIdx.x;
    if (i >= 90112) return;
    const float* s; int off;
    if (i < 4096)       { s = s0; off = 0; }
    else if (i < 8192)  { s = s1; off = 4096; }
    else if (i < 24576) { s = s2; off = 8192; }
    else if (i < 40960) { s = s3; off = 24576; }
    else                { s = s4; off = 40960; }
    st4h(dst + 4 * (size_t)i, ld4(s + 4 * (size_t)(i - off)));
}

// ---------------------------------------------------------------------------
// Mk [50,128] fp32 -> Mkh [64,128] fp16, rows 50..63 zeroed
// ---------------------------------------------------------------------------
__global__ __launch_bounds__(256) void mkcvt(
    const float* __restrict__ Mk, u16* __restrict__ Mkh)
{
    int i = blockIdx.x * 256 + threadIdx.x;   // 2048 float4 slots
    if (i >= 64 * 32) return;
    int row = i >> 5;
    float4 v = (row < MM) ? ld4(Mk + (size_t)row * DQ + (i & 31) * 4)
                          : float4{0.f, 0.f, 0.f, 0.f};
    st4h(Mkh + 4 * (size_t)i, v);
}

// ---------------------------------------------------------------------------
// prep: Xp rows [0,Nc) = fp16(te+qe); rows [Nc,2Nc) = fp16(he+hte+ae+qe);
//       S3p = fp16(he+hte+ae); QEp = fp16(qe)
// ---------------------------------------------------------------------------
__global__ __launch_bounds__(256) void prep128(
    const int* __restrict__ q_data, const int* __restrict__ time_data,
    const int* __restrict__ attempt_data, const int* __restrict__ hint_data,
    const int* __restrict__ hintT_data,
    const float* __restrict__ q_emb, const float* __restrict__ time_emb,
    const float* __restrict__ attempt_emb, const float* __restrict__ ht_emb,
    u16* __restrict__ Xp, u16* __restrict__ S3p, u16* __restrict__ QEp,
    int s0, int CS, int Nc)
{
    int g = blockIdx.x * 256 + threadIdx.x;
    int l = g >> 5;
    int kq = (g & 31) << 2;
    if (l >= Nc) return;
    int n = gmap(l, s0, CS);
    float4 qe  = ld4(q_emb       + (size_t)q_data[n]       * DQ + kq);
    float4 te  = ld4(time_emb    + (size_t)time_data[n]    * DQ + kq);
    float4 ae  = ld4(attempt_emb + (size_t)attempt_data[n] * DQ + kq);
    float4 he  = ld4(ht_emb      + (size_t)hint_data[n]    * DQ + kq);
    float4 hte = ld4(ht_emb      + (size_t)hintT_data[n]   * DQ + kq);
    size_t off = (size_t)l * DQ + kq;
    float4 x1, s3, x2;
    x1.x = te.x + qe.x; x1.y = te.y + qe.y; x1.z = te.z + qe.z; x1.w = te.w + qe.w;
    s3.x = he.x + hte.x + ae.x; s3.y = he.y + hte.y + ae.y;
    s3.z = he.z + hte.z + ae.z; s3.w = he.w + hte.w + ae.w;
    x2.x = s3.x + qe.x; x2.y = s3.y + qe.y; x2.z = s3.z + qe.z; x2.w = s3.w + qe.w;
    st4h(Xp + off, x1);
    st4h(Xp + (size_t)Nc * DQ + off, x2);
    st4h(S3p + off, s3);
    st4h(QEp + off, qe);
}

// ---------------------------------------------------------------------------
// FUSED G1+G2: Y2 = sig(tanh(X @ W1^T + b1) @ W2^T + b2) with MODE-2 epilogue
// (row<Nc: tf; row>=Nc: x3 = qe + v*s3). T never leaves the block: written
// to LDS in the SAME swizzled [128][64]x2 layout a staged tile would have,
// so GEMM2's fragment reads are the verified R7 pattern. BK=64, 4 waves.
// ---------------------------------------------------------------------------
__global__ __launch_bounds__(256, 2) void gemm12(
    const u16* __restrict__ A, const u16* __restrict__ W1h,
    const u16* __restrict__ W2h, const float* __restrict__ b1,
    const float* __restrict__ b2, u16* __restrict__ Yh,
    const u16* __restrict__ QEp, const u16* __restrict__ S3p, int Nc)
{
    __shared__ u16 smem[32768];          // 64KB: At 8192 | Bt 8192 | Tt 16384
    u16* At = smem;
    u16* Bt = smem + 8192;
    u16* Tt = smem + 16384;
    const int tid = threadIdx.x;
    const int row0 = blockIdx.x * 128;
    const int lane = tid & 63, wv = tid >> 6;
    const int wr = (wv >> 1) * 64, wc = (wv & 1) * 64;
    const int q = lane >> 4, c0 = lane & 15;

    floatx4 acc[4][4];
#pragma unroll
    for (int m = 0; m < 4; ++m)
#pragma unroll
        for (int n = 0; n < 4; ++n) acc[m][n] = (floatx4)0.f;

    // ---- GEMM1: X @ W1^T, K=128 ----
    for (int kt = 0; kt < 128; kt += 64) {
#pragma unroll
        for (int j = 0; j < 4; ++j) {
            int f = tid + j * 256; int r = f >> 3; int lg = (f & 7) ^ (r & 7);
            gl16(A + (size_t)(row0 + r) * 128 + kt + lg * 8, &At[f * 8]);
        }
#pragma unroll
        for (int j = 0; j < 4; ++j) {
            int f = tid + j * 256; int r = f >> 3; int lg = (f & 7) ^ (r & 7);
            gl16(W1h + (size_t)r * 128 + kt + lg * 8, &Bt[f * 8]);
        }
        __syncthreads();
#pragma unroll
        for (int kk = 0; kk < 2; ++kk) {
            half8 af[4], bf[4];
#pragma unroll
            for (int m = 0; m < 4; ++m) {
                int row = wr + m * 16 + c0;
                af[m] = *(half8*)&At[row * 64 + ((((kk << 2) | q)) ^ (row & 7)) * 8];
            }
#pragma unroll
            for (int n = 0; n < 4; ++n) {
                int row = wc + n * 16 + c0;
                bf[n] = *(half8*)&Bt[row * 64 + ((((kk << 2) | q)) ^ (row & 7)) * 8];
            }
#pragma unroll
            for (int m = 0; m < 4; ++m)
#pragma unroll
                for (int n = 0; n < 4; ++n)
                    acc[m][n] = __builtin_amdgcn_mfma_f32_16x16x32_f16(af[m], bf[n], acc[m][n], 0, 0, 0);
        }
        __syncthreads();
    }

    // ---- T = tanh(acc + b1) -> Tt (two swizzled [128][64] tiles) ----
    {
        float bv1[4];
#pragma unroll
        for (int n = 0; n < 4; ++n) bv1[n] = b1[wc + n * 16 + c0];
#pragma unroll
        for (int m = 0; m < 4; ++m)
#pragma unroll
            for (int r4 = 0; r4 < 4; ++r4) {
                int row = wr + m * 16 + q * 4 + r4;
#pragma unroll
                for (int n = 0; n < 4; ++n) {
                    int col = wc + n * 16 + c0;
                    float v = tanhfast(acc[m][n][r4] + bv1[n]);
                    int tile = col >> 6, cl = col & 63, gl = cl >> 3;
                    Tt[tile * 8192 + row * 64 + ((gl ^ (row & 7)) << 3) + (cl & 7)] = f2h(v);
                }
            }
    }
#pragma unroll
    for (int m = 0; m < 4; ++m)
#pragma unroll
        for (int n = 0; n < 4; ++n) acc[m][n] = (floatx4)0.f;

    // stage W2 kt=0 alongside T writes (Bt free after GEMM1's final barrier)
#pragma unroll
    for (int j = 0; j < 4; ++j) {
        int f = tid + j * 256; int r = f >> 3; int lg = (f & 7) ^ (r & 7);
        gl16(W2h + (size_t)r * 128 + 0 + lg * 8, &Bt[f * 8]);
    }
    __syncthreads();

    // ---- GEMM2: T @ W2^T, K=128 (T resident in Tt) ----
#pragma unroll
    for (int kt = 0; kt < 2; ++kt) {
#pragma unroll
        for (int kk = 0; kk < 2; ++kk) {
            half8 af[4], bf[4];
#pragma unroll
            for (int m = 0; m < 4; ++m) {
                int row = wr + m * 16 + c0;
                af[m] = *(half8*)&Tt[kt * 8192 + row * 64 + ((((kk << 2) | q)) ^ (row & 7)) * 8];
            }
#pragma unroll
            for (int n = 0; n < 4; ++n) {
                int row = wc + n * 16 + c0;
                bf[n] = *(half8*)&Bt[row * 64 + ((((kk << 2) | q)) ^ (row & 7)) * 8];
            }
#pragma unroll
            for (int m = 0; m < 4; ++m)
#pragma unroll
                for (int n = 0; n < 4; ++n)
                    acc[m][n] = __builtin_amdgcn_mfma_f32_16x16x32_f16(af[m], bf[n], acc[m][n], 0, 0, 0);
        }
        if (kt == 0) {
            __syncthreads();     // Bt reads of kt=0 done
#pragma unroll
            for (int j = 0; j < 4; ++j) {
                int f = tid + j * 256; int r = f >> 3; int lg = (f & 7) ^ (r & 7);
                gl16(W2h + (size_t)r * 128 + 64 + lg * 8, &Bt[f * 8]);
            }
            __syncthreads();     // kt=1 tile staged
        }
    }

    // ---- MODE-2 epilogue ----
    float bv[4];
#pragma unroll
    for (int n = 0; n < 4; ++n) bv[n] = b2[wc + n * 16 + c0];
#pragma unroll
    for (int m = 0; m < 4; ++m)
#pragma unroll
        for (int r4 = 0; r4 < 4; ++r4) {
            int row = row0 + wr + m * 16 + q * 4 + r4;
#pragma unroll
            for (int n = 0; n < 4; ++n) {
                int col = wc + n * 16 + c0;
                float v = sigf(acc[m][n][r4] + bv[n]);
                if (row < Nc) {
                    Yh[(size_t)row * 128 + col] = f2h(v);
                } else {
                    size_t o = (size_t)(row - Nc) * 128 + col;
                    float qe = h2f(QEp[o]), s3 = h2f(S3p[o]);
                    Yh[(size_t)row * 128 + col] = f2h(fmaf(v, s3, qe));
                }
            }
        }
}

// ---------------------------------------------------------------------------
// FUSED G3+wsoftmax: qp = x3 @ W1^T + b1 (kept in LDS, never global);
// ie = qp + tf*te -> RDIE[:,256:384]; logits = qp @ Mkh^T; row softmax;
// w -> Wb (stride 52). Mkh staged once (16KB). Sred aliases smem after
// all LDS GEMM reads complete.
// ---------------------------------------------------------------------------
__global__ __launch_bounds__(256, 2) void gemm3w(
    const u16* __restrict__ X3, const u16* __restrict__ W1h,
    const float* __restrict__ b1, const u16* __restrict__ Mkh,
    const int* __restrict__ tidx, const float* __restrict__ temb,
    const u16* __restrict__ TF, u16* __restrict__ RDIE,
    float* __restrict__ Wb, int s0, int CS)
{
    __shared__ u16 smem[32768];          // At 8192 | Bt 8192 | Tt(qp) 16384
    u16* At = smem;
    u16* Bt = smem + 8192;
    u16* Tt = smem + 16384;
    const int tid = threadIdx.x;
    const int row0 = blockIdx.x * 128;
    const int lane = tid & 63, wv = tid >> 6;
    const int wr = (wv >> 1) * 64, wc = (wv & 1) * 64;
    const int q = lane >> 4, c0 = lane & 15;

    floatx4 acc[4][4];
#pragma unroll
    for (int m = 0; m < 4; ++m)
#pragma unroll
        for (int n = 0; n < 4; ++n) acc[m][n] = (floatx4)0.f;

    // ---- GEMM3: x3 @ W1^T, K=128 ----
    for (int kt = 0; kt < 128; kt += 64) {
#pragma unroll
        for (int j = 0; j < 4; ++j) {
            int f = tid + j * 256; int r = f >> 3; int lg = (f & 7) ^ (r & 7);
            gl16(X3 + (size_t)(row0 + r) * 128 + kt + lg * 8, &At[f * 8]);
        }
#pragma unroll
        for (int j = 0; j < 4; ++j) {
            int f = tid + j * 256; int r = f >> 3; int lg = (f & 7) ^ (r & 7);
            gl16(W1h + (size_t)r * 128 + kt + lg * 8, &Bt[f * 8]);
        }
        __syncthreads();
#pragma unroll
        for (int kk = 0; kk < 2; ++kk) {
            half8 af[4], bf[4];
#pragma unroll
            for (int m = 0; m < 4; ++m) {
                int row = wr + m * 16 + c0;
                af[m] = *(half8*)&At[row * 64 + ((((kk << 2) | q)) ^ (row & 7)) * 8];
            }
#pragma unroll
            for (int n = 0; n < 4; ++n) {
                int row = wc + n * 16 + c0;
                bf[n] = *(half8*)&Bt[row * 64 + ((((kk << 2) | q)) ^ (row & 7)) * 8];
            }
#pragma unroll
            for (int m = 0; m < 4; ++m)
#pragma unroll
                for (int n = 0; n < 4; ++n)
                    acc[m][n] = __builtin_amdgcn_mfma_f32_16x16x32_f16(af[m], bf[n], acc[m][n], 0, 0, 0);
        }
        __syncthreads();
    }

    // ---- qp = acc + b1 -> Tt (swizzled); ie = qp + tf*te -> RDIE ----
    {
        float bv1[4];
#pragma unroll
        for (int n = 0; n < 4; ++n) bv1[n] = b1[wc + n * 16 + c0];
#pragma unroll
        for (int m = 0; m < 4; ++m)
#pragma unroll
            for (int r4 = 0; r4 < 4; ++r4) {
                int rloc = wr + m * 16 + q * 4 + r4;
                int grow = row0 + rloc;
                int nmap = gmap(grow, s0, CS);
                const float* terow = temb + (size_t)tidx[nmap] * 128;
#pragma unroll
                for (int n = 0; n < 4; ++n) {
                    int col = wc + n * 16 + c0;
                    float qp = acc[m][n][r4] + bv1[n];
                    int tile = col >> 6, cl = col & 63, gl = cl >> 3;
                    Tt[tile * 8192 + rloc * 64 + ((gl ^ (rloc & 7)) << 3) + (cl & 7)] = f2h(qp);
                    float tf = h2f(TF[(size_t)grow * 128 + col]);
                    RDIE[(size_t)grow * 384 + 256 + col] = f2h(fmaf(tf, terow[col], qp));
                }
            }
    }
    // stage Mkh (both k-tiles, 16KB) into Bt: tiles [64][64] swizzled
#pragma unroll
    for (int j = 0; j < 4; ++j) {
        int f = tid + j * 256;           // [0,1024)
        int fl = f & 511;
        int ktile = f >> 9;              // 0: k 0..63, 1: k 64..127
        int r = fl >> 3;
        int lg = (fl & 7) ^ (r & 7);
        gl16(Mkh + (size_t)r * 128 + ktile * 64 + lg * 8, &Bt[f * 8]);
    }
    __syncthreads();

    // ---- logits = qp @ Mkh^T (wave = 32 rows x 64 cols, acc2[2][4]) ----
    const int wrW = wv * 32;
    floatx4 acc2[2][4];
#pragma unroll
    for (int m = 0; m < 2; ++m)
#pragma unroll
        for (int n = 0; n < 4; ++n) acc2[m][n] = (floatx4)0.f;
#pragma unroll
    for (int kt = 0; kt < 2; ++kt)
#pragma unroll
        for (int kk = 0; kk < 2; ++kk) {
            half8 af[2], bf[4];
#pragma unroll
            for (int m = 0; m < 2; ++m) {
                int row = wrW + m * 16 + c0;
                af[m] = *(half8*)&Tt[kt * 8192 + row * 64 + ((((kk << 2) | q)) ^ (row & 7)) * 8];
            }
#pragma unroll
            for (int n = 0; n < 4; ++n) {
                int row = n * 16 + c0;
                bf[n] = *(half8*)&Bt[kt * 4096 + row * 64 + ((((kk << 2) | q)) ^ (row & 7)) * 8];
            }
#pragma unroll
            for (int m = 0; m < 2; ++m)
#pragma unroll
                for (int n = 0; n < 4; ++n)
                    acc2[m][n] = __builtin_amdgcn_mfma_f32_16x16x32_f16(af[m], bf[n], acc2[m][n], 0, 0, 0);
        }
    __syncthreads();   // all Tt/Bt reads done; smem reusable as Sred

    // ---- softmax (pitch-67 Sred aliases smem; 34304B <= 64KB) ----
    float* Sred = (float*)smem;
#pragma unroll
    for (int m = 0; m < 2; ++m)
#pragma unroll
        for (int r4 = 0; r4 < 4; ++r4) {
            int row = wrW + m * 16 + q * 4 + r4;
#pragma unroll
            for (int n = 0; n < 4; ++n)
                Sred[row * 67 + n * 16 + c0] = acc2[m][n][r4];
        }
    __syncthreads();

    if (tid < 128) {
        float* s = &Sred[tid * 67];
        float mx = -3.0e38f;
#pragma unroll
        for (int m = 0; m < MM; ++m) mx = fmaxf(mx, s[m]);
        float sum = 0.f;
#pragma unroll
        for (int m = 0; m < MM; ++m) { float e = __expf(s[m] - mx); s[m] = e; sum += e; }
        float inv = 1.f / sum;
#pragma unroll
        for (int m = 0; m < MM; ++m) s[m] *= inv;
        s[50] = 0.f; s[51] = 0.f;
    }
    __syncthreads();

    for (int i = tid; i < 128 * 13; i += 256) {
        int row = i / 13, seg = i - row * 13;
        float4 v;
        v.x = Sred[row * 67 + seg * 4 + 0];
        v.y = Sred[row * 67 + seg * 4 + 1];
        v.z = Sred[row * 67 + seg * 4 + 2];
        v.w = Sred[row * 67 + seg * 4 + 3];
        *(float4*)(Wb + (size_t)(row0 + row) * WSTRIDE + seg * 4) = v;
    }
}

// ---------------------------------------------------------------------------
// fp16 MFMA GEMM (kept for MODE 4 EAtab build and MODE 5 readout), BK=64,
// global_load_lds staging with XOR-granule swizzle (R7-verified).
// ---------------------------------------------------------------------------
template <int MODE>
__global__ __launch_bounds__(256, 2) void gemm16(
    const u16* __restrict__ A, const u16* __restrict__ W0,
    const u16* __restrict__ W1, const float* __restrict__ b0,
    const float* __restrict__ b1, u16* __restrict__ Yh,
    float* __restrict__ Yf,
    u16* __restrict__ AUX, const float* __restrict__ predW,
    int K)
{
    __shared__ u16 smem[2 * 128 * 64];   // 32768 B
    u16* At = smem;
    u16* Bt = smem + 128 * 64;
    const int tid = threadIdx.x;
    const int row0 = blockIdx.x * 128;
    const int by = blockIdx.y;

    const u16* Wp;
    int col0;
    if constexpr (MODE == 4) { Wp = (by < 2) ? W0 : W1; col0 = (by & 1) * 128; }
    else { Wp = W0; col0 = by * 128; }
    const float* bias = (MODE == 4 && by >= 2) ? b1 : b0;

    floatx4 acc[4][4];
#pragma unroll
    for (int m = 0; m < 4; ++m)
#pragma unroll
        for (int n = 0; n < 4; ++n) acc[m][n] = (floatx4)0.f;

    const int lane = tid & 63, wv = tid >> 6;
    const int wr = (wv >> 1) * 64, wc = (wv & 1) * 64;
    const int q = lane >> 4, c0 = lane & 15;

    for (int kt = 0; kt < K; kt += 64) {
#pragma unroll
        for (int j = 0; j < 4; ++j) {
            int f = tid + j * 256;
            int r = f >> 3;
            int lg = (f & 7) ^ (r & 7);
            gl16(A + (size_t)(row0 + r) * K + kt + lg * 8, &At[f * 8]);
        }
#pragma unroll
        for (int j = 0; j < 4; ++j) {
            int f = tid + j * 256;
            int r = f >> 3;
            int lg = (f & 7) ^ (r & 7);
            gl16(Wp + (size_t)(col0 + r) * K + kt + lg * 8, &Bt[f * 8]);
        }
        __syncthreads();
#pragma unroll
        for (int kk = 0; kk < 2; ++kk) {
            half8 af[4], bf[4];
#pragma unroll
            for (int m = 0; m < 4; ++m) {
                int row = wr + m * 16 + c0;
                af[m] = *(half8*)&At[row * 64 + ((((kk << 2) | q)) ^ (row & 7)) * 8];
            }
#pragma unroll
            for (int n = 0; n < 4; ++n) {
                int row = wc + n * 16 + c0;
                bf[n] = *(half8*)&Bt[row * 64 + ((((kk << 2) | q)) ^ (row & 7)) * 8];
            }
#pragma unroll
            for (int m = 0; m < 4; ++m)
#pragma unroll
                for (int n = 0; n < 4; ++n)
                    acc[m][n] = __builtin_amdgcn_mfma_f32_16x16x32_f16(af[m], bf[n], acc[m][n], 0, 0, 0);
        }
        __syncthreads();
    }

    float bv[4];
#pragma unroll
    for (int n = 0; n < 4; ++n) bv[n] = bias[col0 + wc + n * 16 + c0];

    if constexpr (MODE == 5) {
        float pw[4];
#pragma unroll
        for (int n = 0; n < 4; ++n) pw[n] = predW[col0 + wc + n * 16 + c0];
        float* red = (float*)smem;          // [128][33] = 16896 B
#pragma unroll
        for (int m = 0; m < 4; ++m)
#pragma unroll
            for (int r4 = 0; r4 < 4; ++r4) {
                int row = wr + m * 16 + q * 4 + r4;
                float pp = 0.f;
#pragma unroll
                for (int n = 0; n < 4; ++n)
                    pp = fmaf(tanhfast(acc[m][n][r4] + bv[n]), pw[n], pp);
                red[row * 33 + (wv & 1) * 16 + c0] = pp;
            }
        __syncthreads();
        if (tid < 128) {
            float s = 0.f;
#pragma unroll
            for (int j = 0; j < 32; ++j) s += red[tid * 33 + j];
            atomicAdd(&Yf[row0 + tid], s);
        }
    } else { // MODE 4
#pragma unroll
        for (int m = 0; m < 4; ++m)
#pragma unroll
            for (int r4 = 0; r4 < 4; ++r4) {
                int row = row0 + wr + m * 16 + q * 4 + r4;
#pragma unroll
                for (int n = 0; n < 4; ++n) {
                    int col = col0 + wc + n * 16 + c0;
                    float v = acc[m][n][r4] + bv[n];
                    bool isE = (by < 2);
                    v = isE ? sigf(v) : tanhfast(v);
                    AUX[((size_t)row * 256 + col) * 2 + (isE ? 0 : 1)] = f2h(v);
                }
            }
    }
}

// ---------------------------------------------------------------------------
// DKVMN scan v9 (best measured 97.5us): 256 blocks (batch) x 256 threads
// (dim d). LDS double-buffered WT-step w tiles; one-step register ping-pong
// for the broadcast ds_reads; packed-f2 math (mv += w*(a - e*mv)). e/a
// gathered from the per-qa-index table EAtab, prefetched a tile ahead.
// ---------------------------------------------------------------------------
__global__ __launch_bounds__(256, 1) void scan_kernel(
    const float* __restrict__ Wb, const int* __restrict__ qa_data,
    const u32* __restrict__ EAtab,
    const float* __restrict__ Mv0, float* __restrict__ MvSt,
    u16* __restrict__ RDIE, int CS, int s0, int first)
{
    __shared__ float wt[2][WT * WSTRIDE];   // 2 x 520 floats = 4160 B
    const int b = blockIdx.x;
    const int d = threadIdx.x;

    f2 mv[25];
    if (first) {
#pragma unroll
        for (int j = 0; j < 25; ++j) {
            mv[j].x = Mv0[(2 * j) * DV + d];
            mv[j].y = Mv0[(2 * j + 1) * DV + d];
        }
    } else {
#pragma unroll
        for (int j = 0; j < 25; ++j) {
            mv[j].x = MvSt[((size_t)b * MM + 2 * j) * DV + d];
            mv[j].y = MvSt[((size_t)b * MM + 2 * j + 1) * DV + d];
        }
    }

    const float* wbase = Wb + (size_t)b * CS * WSTRIDE;   // rows contiguous
    const int* qap = qa_data + (size_t)b * SQ + s0;
    u16* rp = RDIE + (size_t)b * CS * 384 + d;

    const int NT = CS / WT;
    const bool loader = (d < (WT * WSTRIDE / 4));   // 130 loader threads

    // Preload tile 0: W -> LDS buf0, ea -> regs (index then gather)
    if (loader) *(float4*)&wt[0][d * 4] = ld4(wbase + d * 4);
    u32 ea[WT];
    {
        int qi[WT];
#pragma unroll
        for (int i = 0; i < WT; ++i) qi[i] = qap[i];
#pragma unroll
        for (int i = 0; i < WT; ++i) ea[i] = EAtab[(size_t)qi[i] * DV + d];
    }
    __syncthreads();

    int cur = 0;
    for (int tile = 0; tile < NT; ++tile) {
        // Prefetch next tile (global -> regs); consumed after this tile
        float4 wreg;
        u32 ean[WT];
        const bool havenext = (tile + 1 < NT);
        if (havenext) {
            if (loader) wreg = ld4(wbase + (size_t)(tile + 1) * WT * WSTRIDE + d * 4);
            int qn[WT];
#pragma unroll
            for (int i = 0; i < WT; ++i) qn[i] = qap[(tile + 1) * WT + i];
#pragma unroll
            for (int i = 0; i < WT; ++i) ean[i] = EAtab[(size_t)qn[i] * DV + d];
        }

        // Register ping-pong over steps; preload step 0
        float4 wpp[2][13];
#pragma unroll
        for (int i = 0; i < 13; ++i)
            wpp[0][i] = *(const float4*)&wt[cur][i * 4];

#pragma unroll
        for (int s = 0; s < WT; ++s) {
            // issue step s+1's broadcast ds_reads into the other bank
            if (s + 1 < WT) {
#pragma unroll
                for (int i = 0; i < 13; ++i)
                    wpp[(s + 1) & 1][i] =
                        *(const float4*)&wt[cur][(s + 1) * WSTRIDE + i * 4];
            }
            const f2* w2 = (const f2*)wpp[s & 1];
            u32 eav = ea[s];
            float e = h2f((u16)(eav & 0xffff));
            float a = h2f((u16)(eav >> 16));
            f2 e2; e2.x = e; e2.y = e;
            f2 a2; a2.x = a; a2.y = a;
            f2 r0 = (f2)0.f, r1 = (f2)0.f, r2 = (f2)0.f, r3 = (f2)0.f;
#pragma unroll
            for (int j = 0; j < 24; j += 4) {
                f2 w_0 = w2[j + 0], w_1 = w2[j + 1], w_2 = w2[j + 2], w_3 = w2[j + 3];
                r0 += w_0 * mv[j + 0];
                r1 += w_1 * mv[j + 1];
                r2 += w_2 * mv[j + 2];
                r3 += w_3 * mv[j + 3];
                f2 t0 = a2 - e2 * mv[j + 0];
                f2 t1 = a2 - e2 * mv[j + 1];
                f2 t2 = a2 - e2 * mv[j + 2];
                f2 t3 = a2 - e2 * mv[j + 3];
                mv[j + 0] += w_0 * t0;
                mv[j + 1] += w_1 * t1;
                mv[j + 2] += w_2 * t2;
                mv[j + 3] += w_3 * t3;
            }
            {
                f2 w24 = w2[24];
                r0 += w24 * mv[24];
                f2 t = a2 - e2 * mv[24];
                mv[24] += w24 * t;
            }
            f2 rs = (r0 + r1) + (r2 + r3);
            rp[(size_t)(tile * WT + s) * 384] = f2h(rs.x + rs.y);
        }

        if (havenext) {
            if (loader) *(float4*)&wt[1 - cur][d * 4] = wreg;
#pragma unroll
            for (int i = 0; i < WT; ++i) ea[i] = ean[i];
            __syncthreads();
            cur ^= 1;
        }
    }

#pragma unroll
    for (int j = 0; j < 25; ++j) {
        MvSt[((size_t)b * MM + 2 * j) * DV + d]     = mv[j].x;
        MvSt[((size_t)b * MM + 2 * j + 1) * DV + d] = mv[j].y;
    }
}

// ---------------------------------------------------------------------------
// loss + outputs
// ---------------------------------------------------------------------------
__global__ __launch_bounds__(256) void loss_part(
    const float* __restrict__ P, const int* __restrict__ target,
    const float* __restrict__ pred_b, float* __restrict__ out,
    float* __restrict__ R2, int s0, int CS, int Nc)
{
    int l = blockIdx.x * 256 + threadIdx.x;
    float le = 0.f, mf = 0.f;
    if (l < Nc) {
        int n = gmap(l, s0, CS);
        float p = P[l] + pred_b[0];
        int t = target[n];
        float y = (t >= 1) ? (float)(t - 1) : 0.f;
        float sig = 1.f / (1.f + __expf(-p));
        if (t >= 1) {
            mf = 1.f;
            le = fmaxf(p, 0.f) + log1pf(__expf(-fabsf(p))) - p * y;
        }
        out[1 + n] = sig * mf;
        out[1 + NROWS + n] = y * mf;
    }
#pragma unroll
    for (int off = 32; off; off >>= 1) {
        le += __shfl_down(le, off);
        mf += __shfl_down(mf, off);
    }
    __shared__ float sl[4], sm[4];
    int wid = threadIdx.x >> 6;
    if ((threadIdx.x & 63) == 0) { sl[wid] = le; sm[wid] = mf; }
    __syncthreads();
    if (threadIdx.x == 0) {
        atomicAdd(R2, sl[0] + sl[1] + sl[2] + sl[3]);
        atomicAdd(R2 + 1, sm[0] + sm[1] + sm[2] + sm[3]);
    }
}

__global__ void loss_fin(const float* __restrict__ R2, float* __restrict__ out)
{
    out[0] = R2[0] / fmaxf(R2[1], 1.f);
}

// ---------------------------------------------------------------------------
extern "C" void kernel_launch(void* const* d_in, const int* in_sizes, int n_in,
                              void* d_out, int out_size, void* d_ws, size_t ws_size,
                              hipStream_t stream)
{
    const int* q_data       = (const int*)d_in[0];
    const int* qa_data      = (const int*)d_in[1];
    const int* target       = (const int*)d_in[2];
    const int* time_data    = (const int*)d_in[3];
    const int* attempt_data = (const int*)d_in[4];
    const int* hint_data    = (const int*)d_in[5];
    const int* hintT_data   = (const int*)d_in[6];
    const float* q_emb    = (const float*)d_in[7];
    const float* qa_emb   = (const float*)d_in[8];
    const float* time_emb = (const float*)d_in[9];
    const float* att_emb  = (const float*)d_in[10];
    const float* ht_emb   = (const float*)d_in[11];
    const float* Mk       = (const float*)d_in[12];
    const float* Mv0      = (const float*)d_in[13];
    const float* diff_W   = (const float*)d_in[14];
    const float* diff_b   = (const float*)d_in[15];
    const float* diff2_W  = (const float*)d_in[16];
    const float* diff2_b  = (const float*)d_in[17];
    const float* erase_W  = (const float*)d_in[18];
    const float* erase_b  = (const float*)d_in[19];
    const float* add_W    = (const float*)d_in[20];
    const float* add_b    = (const float*)d_in[21];
    const float* read_W   = (const float*)d_in[22];
    const float* read_b   = (const float*)d_in[23];
    const float* pred_W   = (const float*)d_in[24];
    const float* pred_b   = (const float*)d_in[25];
    float* out = (float*)d_out;
    (void)in_sizes; (void)n_in; (void)out_size;

    // Adaptive chunking over S (CS must be divisible by WT=10).
    static const int cs_opts[] = {500, 250, 100, 50, 20, 10};
    const size_t FIXED = 44700000ull;
    int CS = 0;
    for (int i = 0; i < 6; ++i) {
        size_t need = (size_t)NB * cs_opts[i] * 2016ull + FIXED;
        if (need <= ws_size) { CS = cs_opts[i]; break; }
    }
    if (CS == 0) return;
    const int NCH = SQ / CS;
    const int Nc = NB * CS;

    // Workspace layout (16B-aligned sections)
    float* MvSt  = (float*)d_ws;                         // [NB*MM*DV]
    float* wbuf  = MvSt + (size_t)NB * MM * DV;          // [Nc*52]
    float* bufP  = wbuf + (size_t)Nc * WSTRIDE;          // [Nc]
    float* bufR2 = bufP + Nc;                            // [4]
    u16*  Xp     = (u16*)(bufR2 + 4);                    // [2Nc*128]
    u16*  S3p    = Xp + (size_t)2 * Nc * 128;            // [Nc*128]
    u16*  QEp    = S3p + (size_t)Nc * 128;               // [Nc*128]
    u16*  RDIE   = QEp + (size_t)Nc * 128;               // [Nc*384]
    u16*  dWh    = RDIE + (size_t)Nc * 384;              // 16384
    u16*  d2Wh   = dWh + 16384;                          // 16384
    u16*  eWh    = d2Wh + 16384;                         // 65536
    u16*  aWh    = eWh + 65536;                          // 65536
    u16*  rWh    = aWh + 65536;                          // 196608
    u16*  qaEh   = rWh + 196608;                         // 5,120,256
    u16*  Mkh    = qaEh + 5120256;                       // 8,192 (64x128)
    u32*  EAtab  = (u32*)(Mkh + 8192);                   // [NQA*256] u32 = 20.6 MB

    // Fused one-time weight conversions (5 matrices -> contiguous dWh..rWh)
    wcvt<<<352, 256, 0, stream>>>(diff_W, diff2_W, erase_W, add_W, read_W, dWh);
    cvt16<<<5001, 256, 0, stream>>>(qa_emb, qaEh, 5120256 / 4);
    mkcvt<<<8, 256, 0, stream>>>(Mk, Mkh);
    hipMemsetAsync(bufR2, 0, 4 * sizeof(float), stream);

    // One-time e/a gate TABLE over all distinct qa indices (NQA rows)
    gemm16<4><<<dim3(NQA / 128, 4), 256, 0, stream>>>(
        qaEh, eWh, aWh, erase_b, add_b, nullptr, nullptr,
        (u16*)EAtab, nullptr, 256);

    for (int c = 0; c < NCH; ++c) {
        const int s0 = c * CS;

        prep128<<<Nc / 8, 256, 0, stream>>>(
            q_data, time_data, attempt_data, hint_data, hintT_data,
            q_emb, time_emb, att_emb, ht_emb, Xp, S3p, QEp, s0, CS, Nc);

        // FUSED G1+G2: tf (rows<Nc) and x3 (rows>=Nc) in one pass
        gemm12<<<2 * Nc / 128, 256, 0, stream>>>(
            Xp, dWh, d2Wh, diff_b, diff2_b, Xp, QEp, S3p, Nc);

        // FUSED G3+wsoftmax: qp in LDS; ie -> RDIE; w -> wbuf
        gemm3w<<<Nc / 128, 256, 0, stream>>>(
            Xp + (size_t)Nc * 128, dWh, diff_b, Mkh,
            time_data, time_emb, Xp, RDIE, wbuf, s0, CS);

        // scan -> RD fp16 into RDIE[:,0:256); e/a gathered from EAtab
        scan_kernel<<<NB, DV, 0, stream>>>(
            wbuf, qa_data, EAtab, Mv0, MvSt, RDIE, CS, s0, c == 0 ? 1 : 0);

        hipMemsetAsync(bufP, 0, (size_t)Nc * sizeof(float), stream);
        // G5: rc = tanh([rd|ie] @ read_W^T + b); pred partials -> bufP
        gemm16<5><<<dim3(Nc / 128, 4), 256, 0, stream>>>(
            RDIE, rWh, nullptr, read_b, nullptr, nullptr, bufP,
            nullptr, pred_W, 384);

        loss_part<<<Nc / 256, 256, 0, stream>>>(bufP, target, pred_b, out, bufR2, s0, CS, Nc);
    }

    loss_fin<<<1, 1, 0, stream>>>(bufR2, out);
}